// Round 7
// baseline (3604.463 us; speedup 1.0000x reference)
//
#include <hip/hip_runtime.h>
#include <cmath>

#define TT 64
#define BB 64
#define SS 512
#define AA 16
#define RR 64
#define HH 32
#define EPS 1e-6f

// ws layout in floats
#define WS_TR   0                         // transition [A][S][S] = 4194304
#define WS_AT   4194304                   // alpha_a transposed [T][A][B] = 65536
#define WS_PDF  (WS_AT + 65536)           // tau_pdf [32]
#define WS_X0   (WS_PDF + 32)             // sigma buf 0 [B][S] = 32768
#define WS_X1   (WS_X0 + 32768)           // sigma buf 1
#define WS_X2   (WS_X1 + 32768)           // sigma buf 2
#define WS_BAR  (WS_X2 + 32768)           // barrier region (1024 uints)
#define WS_G    (WS_BAR + 1024)           // Gacc [64 t][64 n] = 4096

#define AGENT __HIP_MEMORY_SCOPE_AGENT

__device__ __forceinline__ float aload(const float* p) {
  return __hip_atomic_load(p, __ATOMIC_RELAXED, AGENT);
}
__device__ __forceinline__ void astore(float* p, float v) {
  __hip_atomic_store(p, v, __ATOMIC_RELAXED, AGENT);
}
__device__ __forceinline__ unsigned long long aload64(const unsigned long long* p) {
  return __hip_atomic_load(p, __ATOMIC_RELAXED, AGENT);
}
__device__ __forceinline__ void astore64(unsigned long long* p, unsigned long long v) {
  __hip_atomic_store(p, v, __ATOMIC_RELAXED, AGENT);
}

union U2 { unsigned long long u; float2 f; };

// ---------------- transition
__global__ __launch_bounds__(256) void k_trans2(const float* __restrict__ u,
                                                const float* __restrict__ v,
                                                float* __restrict__ Tr) {
  int bx = blockIdx.x;
  int k = bx >> 5, ic = bx & 31, i0 = ic * 16;
  __shared__ float urot_s[16][68];
  __shared__ float ut_s[64][68];
  __shared__ float w_s[16][516];
  int tid = threadIdx.x;
  int lane = tid & 63, wv = tid >> 6;

  float vkm = v[k*RR + lane];
  float n2 = vkm * vkm;
  #pragma unroll
  for (int o = 32; o > 0; o >>= 1) n2 += __shfl_xor(n2, o, 64);

  #pragma unroll
  for (int r = 0; r < 4; r++) {
    int il = wv*4 + r;
    float um = u[(size_t)(i0 + il)*RR + lane];
    float dt = um * vkm;
    #pragma unroll
    for (int o = 32; o > 0; o >>= 1) dt += __shfl_xor(dt, o, 64);
    urot_s[il][lane] = um - (2.f * dt / n2) * vkm;
  }

  int il = tid >> 4, jl4 = (tid & 15) * 4;
  for (int jt = 0; jt < 8; jt++) {
    __syncthreads();
    #pragma unroll
    for (int q = 0; q < 4; q++) {
      int fi = q*256 + tid;
      int r = fi >> 4, c4 = (fi & 15) * 4;
      float4 uu = *(const float4*)(u + (size_t)(jt*64 + r)*RR + c4);
      ut_s[c4+0][r] = uu.x; ut_s[c4+1][r] = uu.y;
      ut_s[c4+2][r] = uu.z; ut_s[c4+3][r] = uu.w;
    }
    __syncthreads();
    float4 acc = {0.f, 0.f, 0.f, 0.f};
    #pragma unroll 8
    for (int m = 0; m < 64; m++) {
      float ur = urot_s[il][m];
      float4 uu = *(const float4*)&ut_s[m][jl4];
      acc.x = fmaf(ur, uu.x, acc.x);
      acc.y = fmaf(ur, uu.y, acc.y);
      acc.z = fmaf(ur, uu.z, acc.z);
      acc.w = fmaf(ur, uu.w, acc.w);
    }
    *(float4*)&w_s[il][jt*64 + jl4] = acc;
  }
  __syncthreads();

  #pragma unroll
  for (int r = 0; r < 4; r++) {
    int ir = wv*4 + r;
    float vals[8]; float mx = -1e30f;
    #pragma unroll
    for (int q = 0; q < 8; q++) { vals[q] = w_s[ir][q*64 + lane]; mx = fmaxf(mx, vals[q]); }
    #pragma unroll
    for (int o = 32; o > 0; o >>= 1) mx = fmaxf(mx, __shfl_xor(mx, o, 64));
    float sm = 0.f;
    #pragma unroll
    for (int q = 0; q < 8; q++) { vals[q] = expf(vals[q] - mx); sm += vals[q]; }
    #pragma unroll
    for (int o = 32; o > 0; o >>= 1) sm += __shfl_xor(sm, o, 64);
    float inv = 1.f / sm;
    #pragma unroll
    for (int q = 0; q < 8; q++)
      Tr[((size_t)k*SS + (i0 + ir))*SS + q*64 + lane] = vals[q] * inv;
  }
}

// ---------------- alpha_a transposed [T][A][B]
__global__ __launch_bounds__(256) void k_alpha_a(const float* __restrict__ lpu,
                                                 float* __restrict__ aT) {
  int idx = blockIdx.x*256 + threadIdx.x;
  int t = idx >> 6, n = idx & 63;
  const float* x = lpu + (size_t)idx * AA;
  float xs[AA]; float m = -1e30f;
  #pragma unroll
  for (int k = 0; k < AA; k++) { xs[k] = x[k]; m = fmaxf(m, xs[k]); }
  float s = 0.f;
  #pragma unroll
  for (int k = 0; k < AA; k++) { xs[k] = expf(xs[k]-m); s += xs[k]; }
  float inv = 1.f/s;
  #pragma unroll
  for (int k = 0; k < AA; k++) aT[t*(AA*BB) + k*BB + n] = xs[k]*inv;
}

// ---------------- Poisson pdf
__global__ void k_taupdf(const float* __restrict__ tau, float* __restrict__ pdf) {
  __shared__ float pl[HH]; __shared__ float ss;
  int tid = threadIdx.x;
  float rate = log1pf(expf(tau[0]));
  if (tid < HH) {
    float kk = (float)(tid+1);
    pl[tid] = expf(kk*logf(rate) - rate - lgammaf(kk+1.f));
  }
  __syncthreads();
  if (tid == 0) { float s = 0.f; for (int h = 0; h < HH; h++) s += pl[h]; ss = 1.f/s; }
  __syncthreads();
  if (tid < HH) pdf[tid] = pl[tid]*ss;
}

// ---------------- zero X1/X2, barrier region, Gacc, alpha_pi
__global__ __launch_bounds__(256) void k_zero(float* __restrict__ X1,
                                              float* __restrict__ X2,
                                              unsigned* __restrict__ bar,
                                              float* __restrict__ alpha_pi,
                                              float* __restrict__ Gacc) {
  int idx = blockIdx.x*256 + threadIdx.x;   // grid 256*256 = 65536
  if (idx < 32768) { X1[idx] = 0.f; X2[idx] = 0.f; }
  if (idx < 1024) bar[idx] = 0u;
  if (idx < 4096) Gacc[idx] = 0.f;
  alpha_pi[idx] = 0.f;                      // 65536 floats
}

// ---------------- persistent scan: 256 blocks x 1024 thr (16 waves/CU = 4/SIMD)
// amdgpu_waves_per_eu(4,4): pins 4 waves/EU -> VGPR budget 128/wave. The
// launch_bounds second arg (r6) did NOT achieve this: compiler kept 64 VGPR
// and spilled the ~116-float GEMM working set to scratch (FETCH 4.5 GB).
// r2 structure (atomicAdd X-rotation) + k-split GEMM across thread-halves
// (kh = tid>>9), cross-kh combine via LDS, lpo prefetch into regs. Tr slice
// (64 KB, time-invariant) in LDS. Normalization carried one step behind via
// scalar G[n]; alpha_b written unnormalized, fixed by k_norm.
__global__ __launch_bounds__(1024)
__attribute__((amdgpu_waves_per_eu(4, 4)))
void k_scan(const float* __restrict__ Tr,
            const float* __restrict__ aT,
            const float* __restrict__ lpo,
            const float* __restrict__ b,
            float* __restrict__ X0,
            float* __restrict__ X1,
            float* __restrict__ X2,
            float* __restrict__ alpha_b,
            float* __restrict__ Gacc,
            unsigned* __restrict__ bar) {
  __shared__ float TrL[16*32*32];  // 64 KB staged transition slice [k][i_local][j_local]
  __shared__ float bel_s[32*68];   // stride 68: 8 ii-rows hit 8 distinct bank groups
  __shared__ float a_s[16*64];
  __shared__ float red_s[64*32];   // kh=1 GEMM partials [n][j_local]
  __shared__ float invG_l[64];
  int tid = threadIdx.x, bx = blockIdx.x;
  int jc = bx & 15, ic = bx >> 4;
  int i0 = ic*32, j0 = jc*32;
  int g = bx & 7;
  unsigned* arr = bar + g*32;
  unsigned* gcnt = bar + 256;
  unsigned* rel = bar + 288 + g*32;

  // one-time stage of Tr slice: 4096 float4 over 1024 threads
  #pragma unroll
  for (int q = 0; q < 4; q++) {
    int f = q*1024 + tid;
    int k = f >> 8, rem = f & 255;
    int i = rem >> 3, j4 = rem & 7;
    float4 tv = *(const float4*)(Tr + ((size_t)k*SS + i0 + i)*SS + j0 + j4*4);
    *(float4*)&TrL[(k*32 + i)*32 + j4*4] = tv;
  }

  int nn = tid >> 4, il2 = (tid & 15)*2;   // bel-pass mapping: thread -> (n, 2 i's)
  float2 lp_pf;                            // prefetched lpo[t] row (used at t+1)

  for (int t = 0; t < TT; t++) {
    const float* Xr; float* Xw; float* Xz;
    {
      int r = t % 3;
      if (r == 0)      { Xr = X0; Xw = X1; Xz = X2; }
      else if (r == 1) { Xr = X1; Xw = X2; Xz = X0; }
      else             { Xr = X2; Xw = X0; Xz = X1; }
    }

    // zero next-next buffer (nobody reads/writes it this step)
    { int g2 = bx*1024 + tid; if (g2 < 32768) astore(Xz + g2, 0.f); }

    // invG (scalar per n) from two steps back; 1.0 for t<2
    if (tid < 64)
      invG_l[tid] = (t >= 2) ? 1.f / aload(Gacc + (size_t)(t-2)*64 + tid) : 1.0f;
    __syncthreads();

    // bel pass: thread's 2 i's; uses prefetched lpo[t-1]
    if (t == 0) {
      float2 bb = *(const float2*)(b + (size_t)nn*SS + i0 + il2);
      bel_s[(il2+0)*68 + nn] = bb.x;
      bel_s[(il2+1)*68 + nn] = bb.y;
    } else {
      size_t off = (size_t)nn*SS + i0 + il2;
      U2 c; c.u = aload64((const unsigned long long*)Xr + (off >> 1));
      float invGn = invG_l[nn];
      float v0 = fmaf(c.f.x, invGn, EPS) * expf(lp_pf.x);
      float v1 = fmaf(c.f.y, invGn, EPS) * expf(lp_pf.y);
      bel_s[(il2+0)*68 + nn] = v0;
      bel_s[(il2+1)*68 + nn] = v1;
      if (ic == jc) {
        U2 p; p.f.x = v0; p.f.y = v1;
        astore64((unsigned long long*)(alpha_b + ((size_t)(t-1)*BB)*SS) + (off >> 1), p.u);
      }
    }
    if (tid < 256) *(float4*)&a_s[tid*4] = *(const float4*)(aT + (size_t)t*1024 + tid*4);
    __syncthreads();

    // prefetch lpo[t] row for next step's bel pass (latency hidden by GEMM+barrier)
    lp_pf = *(const float2*)(lpo + (size_t)t*BB*SS + (size_t)nn*SS + i0 + il2);

    // diagonal blocks: partial G(t-1) over this i-slice (consumed at t+1)
    if (t >= 1 && ic == jc && tid < 64) {
      float s = 0.f;
      #pragma unroll
      for (int il = 0; il < 32; il++) s += bel_s[il*68 + tid];
      atomicAdd(Gacc + (size_t)(t-1)*64 + tid, s);
    }

    // GEMM (all operands in LDS), k-split across thread-halves
    int jq = tid & 7, ii = (tid >> 3) & 7, nq = (tid >> 6) & 7, kh = tid >> 9;
    int n0 = nq*8;
    float4 acc[8];
    #pragma unroll
    for (int m = 0; m < 8; m++) acc[m] = make_float4(0.f, 0.f, 0.f, 0.f);
    const float* TrBase = TrL + ii*32 + jq*4;

    // bf is kb-invariant: load once
    float bf[4][8];
    #pragma unroll
    for (int io = 0; io < 4; io++) {
      *(float4*)&bf[io][0] = *(float4*)&bel_s[(io*8+ii)*68 + n0];
      *(float4*)&bf[io][4] = *(float4*)&bel_s[(io*8+ii)*68 + n0 + 4];
    }

    #pragma unroll
    for (int kq = 0; kq < 2; kq++) {
      int kb = kh*2 + kq;
      float af[4][8];
      #pragma unroll
      for (int kk = 0; kk < 4; kk++) {
        *(float4*)&af[kk][0] = *(float4*)&a_s[(kb*4+kk)*64 + n0];
        *(float4*)&af[kk][4] = *(float4*)&a_s[(kb*4+kk)*64 + n0 + 4];
      }
      #pragma unroll
      for (int io = 0; io < 4; io++) {
        #pragma unroll
        for (int kk = 0; kk < 4; kk++) {
          float4 tv = *(const float4*)(TrBase + (kb*4+kk)*1024 + io*256);
          #pragma unroll
          for (int m = 0; m < 8; m++) {
            float w = af[kk][m] * bf[io][m];
            acc[m].x = fmaf(w, tv.x, acc[m].x);
            acc[m].y = fmaf(w, tv.y, acc[m].y);
            acc[m].z = fmaf(w, tv.z, acc[m].z);
            acc[m].w = fmaf(w, tv.w, acc[m].w);
          }
        }
      }
    }

    #pragma unroll
    for (int m = 0; m < 8; m++) {
      #pragma unroll
      for (int o = 8; o <= 32; o <<= 1) {
        acc[m].x += __shfl_xor(acc[m].x, o, 64);
        acc[m].y += __shfl_xor(acc[m].y, o, 64);
        acc[m].z += __shfl_xor(acc[m].z, o, 64);
        acc[m].w += __shfl_xor(acc[m].w, o, 64);
      }
    }
    // kh=1 half deposits partials in LDS
    if (ii == 0 && kh == 1) {
      #pragma unroll
      for (int m = 0; m < 8; m++)
        *(float4*)&red_s[(n0+m)*32 + jq*4] = acc[m];
    }
    __syncthreads();
    // kh=0 half combines and issues the global atomics (16-way over ic, as r2)
    if (ii == 0 && kh == 0) {
      #pragma unroll
      for (int m = 0; m < 8; m++) {
        float4 r = *(const float4*)&red_s[(n0+m)*32 + jq*4];
        float* dst = Xw + (size_t)(n0+m)*SS + j0 + jq*4;
        atomicAdd(dst+0, acc[m].x + r.x);
        atomicAdd(dst+1, acc[m].y + r.y);
        atomicAdd(dst+2, acc[m].z + r.z);
        atomicAdd(dst+3, acc[m].w + r.w);
      }
    }

    // hierarchical barrier, epoch e = t+1 (monotonic counters, no reset)
    __syncthreads();
    if (tid == 0) {
      unsigned e = (unsigned)(t + 1);
      unsigned np = __hip_atomic_fetch_add(arr, 1u, __ATOMIC_RELEASE, AGENT);
      if (np == e*32u - 1u) {                       // last arrival of this group
        unsigned gp = __hip_atomic_fetch_add(gcnt, 1u, __ATOMIC_RELEASE, AGENT);
        if (gp == e*8u - 1u) {                      // last group: broadcast release
          #pragma unroll
          for (int g2 = 0; g2 < 8; g2++)
            __hip_atomic_store(bar + 288 + g2*32, e, __ATOMIC_RELAXED, AGENT);
        }
      }
      while (__hip_atomic_load(rel, __ATOMIC_RELAXED, AGENT) < e)
        __builtin_amdgcn_s_sleep(1);
      __atomic_signal_fence(__ATOMIC_ACQUIRE);
    }
    __syncthreads();
  }
}

// ---------------- normalize alpha_b rows t=0..62 by invG (row 63 done in k_lastbel)
__global__ __launch_bounds__(128) void k_norm(float* __restrict__ alpha_b,
                                              const float* __restrict__ Gacc) {
  int row = blockIdx.x;                 // 4032 = 63 t * 64 n
  int t = row >> 6, n = row & 63;
  float inv = 1.f / Gacc[t*64 + n];
  float4* p = (float4*)(alpha_b + ((size_t)t*BB + n)*SS);
  float4 x = p[threadIdx.x];
  x.x *= inv; x.y *= inv; x.z *= inv; x.w *= inv;
  p[threadIdx.x] = x;
}

// ---------------- final belief (t=63) from X1 (apply invG(62))
__global__ __launch_bounds__(512) void k_lastbel(const float* __restrict__ X,
                                                 const float* __restrict__ lpo,
                                                 const float* __restrict__ Gacc,
                                                 float* __restrict__ alpha_b) {
  __shared__ float red[512];
  int n = blockIdx.x, j = threadIdx.x;
  float invG = 1.f / Gacc[62*64 + n];
  size_t off = (size_t)n*SS + j;
  float gv = fmaf(X[off], invG, EPS) * expf(lpo[((size_t)63*BB + n)*SS + j]);
  red[j] = gv; __syncthreads();
  for (int s = 256; s > 0; s >>= 1) { if (j < s) red[j] += red[j+s]; __syncthreads(); }
  float inv = 1.f / red[0];
  alpha_b[((size_t)63*BB + n)*SS + j] = gv * inv;
}

// ---------------- plan(): 512 blocks (n x hk-eighth) x 256 thr, 8t x 2hk reg tile
__global__ __launch_bounds__(256) void k_pi(const float* __restrict__ alpha_b,
                                            const float* __restrict__ value,
                                            const float* __restrict__ pdf,
                                            float* __restrict__ alpha_pi) {
  __shared__ float Ab_l[64][132];   // i-tile of 128, pad 4
  __shared__ float lg[64][68];      // logits [t][hk_local 64]
  __shared__ float pdf_l[HH];
  int tid = threadIdx.x, bx = blockIdx.x;
  int n = bx >> 3, e = bx & 7;
  if (tid < HH) pdf_l[tid] = pdf[tid];
  int hkg = tid >> 3, tg = tid & 7;
  int hk0 = e*64 + hkg*2;
  const float* V0 = value + (((size_t)(hk0    >> 4)*BB + n)*AA + (hk0     & 15))*SS;
  const float* V1 = value + (((size_t)((hk0+1) >> 4)*BB + n)*AA + ((hk0+1) & 15))*SS;

  float4 a0[8], a1[8];
  #pragma unroll
  for (int m = 0; m < 8; m++) { a0[m] = make_float4(0,0,0,0); a1[m] = make_float4(0,0,0,0); }

  for (int it = 0; it < 4; it++) {
    __syncthreads();
    #pragma unroll
    for (int q = 0; q < 8; q++) {
      int idx = q*256 + tid;
      int tt = idx >> 5, il4 = (idx & 31)*4;
      float4 ab = *(const float4*)(alpha_b + ((size_t)tt*BB + n)*SS + it*128 + il4);
      *(float4*)&Ab_l[tt][il4] = ab;
    }
    __syncthreads();
    #pragma unroll 4
    for (int iq = 0; iq < 32; iq++) {
      float4 v0 = *(const float4*)(V0 + it*128 + iq*4);
      float4 v1 = *(const float4*)(V1 + it*128 + iq*4);
      #pragma unroll
      for (int tt = 0; tt < 8; tt++) {
        float4 ab = *(const float4*)&Ab_l[tt*8 + tg][iq*4];
        a0[tt].x = fmaf(ab.x, v0.x, a0[tt].x);
        a0[tt].y = fmaf(ab.y, v0.y, a0[tt].y);
        a0[tt].z = fmaf(ab.z, v0.z, a0[tt].z);
        a0[tt].w = fmaf(ab.w, v0.w, a0[tt].w);
        a1[tt].x = fmaf(ab.x, v1.x, a1[tt].x);
        a1[tt].y = fmaf(ab.y, v1.y, a1[tt].y);
        a1[tt].z = fmaf(ab.z, v1.z, a1[tt].z);
        a1[tt].w = fmaf(ab.w, v1.w, a1[tt].w);
      }
    }
  }
  #pragma unroll
  for (int tt = 0; tt < 8; tt++) {
    lg[tt*8 + tg][hkg*2 + 0] = a0[tt].x + a0[tt].y + a0[tt].z + a0[tt].w;
    lg[tt*8 + tg][hkg*2 + 1] = a1[tt].x + a1[tt].y + a1[tt].z + a1[tt].w;
  }
  __syncthreads();

  // softmax over k for (t, local h): 64t x 4h = 256 threads
  {
    int t = tid >> 2, hh = tid & 3;
    float* row = &lg[t][hh*16];
    float m = row[0];
    #pragma unroll
    for (int k2 = 1; k2 < 16; k2++) m = fmaxf(m, row[k2]);
    float ex[16]; float s = 0.f;
    #pragma unroll
    for (int k2 = 0; k2 < 16; k2++) { ex[k2] = expf(row[k2]-m); s += ex[k2]; }
    float w = pdf_l[e*4 + hh] / s;
    #pragma unroll
    for (int k2 = 0; k2 < 16; k2++) row[k2] = ex[k2]*w;
  }
  __syncthreads();

  // combine 4 local h and atomic into alpha_pi
  #pragma unroll
  for (int q = 0; q < 4; q++) {
    int idx = q*256 + tid;           // 1024 = 64t x 16k
    int t = idx >> 4, k2 = idx & 15;
    float s = lg[t][0*16+k2] + lg[t][1*16+k2] + lg[t][2*16+k2] + lg[t][3*16+k2];
    atomicAdd(alpha_pi + ((size_t)t*BB + n)*AA + k2, s);
  }
}

extern "C" void kernel_launch(void* const* d_in, const int* in_sizes, int n_in,
                              void* d_out, int out_size, void* d_ws, size_t ws_size,
                              hipStream_t stream) {
  const float* lpo   = (const float*)d_in[0];
  const float* lpu   = (const float*)d_in[1];
  const float* value = (const float*)d_in[2];
  const float* b     = (const float*)d_in[3];
  const float* u     = (const float*)d_in[4];
  const float* v     = (const float*)d_in[5];
  const float* tau   = (const float*)d_in[6];
  float* out = (float*)d_out;
  float* ws  = (float*)d_ws;

  float* Tr  = ws + WS_TR;
  float* aT  = ws + WS_AT;
  float* pdf = ws + WS_PDF;
  float* X0  = ws + WS_X0;
  float* X1  = ws + WS_X1;
  float* X2  = ws + WS_X2;
  unsigned* bar = (unsigned*)(ws + WS_BAR);
  float* Gacc = ws + WS_G;

  float* alpha_b  = out;
  float* alpha_pi = out + (size_t)TT*BB*SS;

  hipLaunchKernelGGL(k_trans2,  dim3(512), dim3(256), 0, stream, u, v, Tr);
  hipLaunchKernelGGL(k_alpha_a, dim3(16),  dim3(256), 0, stream, lpu, aT);
  hipLaunchKernelGGL(k_taupdf,  dim3(1),   dim3(64),  0, stream, tau, pdf);
  hipLaunchKernelGGL(k_zero,    dim3(256), dim3(256), 0, stream, X1, X2, bar, alpha_pi, Gacc);

  void* args[10];
  args[0] = (void*)&Tr;  args[1] = (void*)&aT;  args[2] = (void*)&lpo;
  args[3] = (void*)&b;   args[4] = (void*)&X0;  args[5] = (void*)&X1;
  args[6] = (void*)&X2;  args[7] = (void*)&alpha_b; args[8] = (void*)&Gacc;
  args[9] = (void*)&bar;
  hipLaunchCooperativeKernel(k_scan, dim3(256), dim3(1024), args, 0, stream);

  hipLaunchKernelGGL(k_norm,    dim3(4032), dim3(128), 0, stream, alpha_b, Gacc);
  hipLaunchKernelGGL(k_lastbel, dim3(64), dim3(512), 0, stream, X1, lpo, Gacc, alpha_b);
  hipLaunchKernelGGL(k_pi, dim3(512), dim3(256), 0, stream, alpha_b, value, pdf, alpha_pi);
}

// Round 8
// 1293.914 us; speedup vs baseline: 2.7857x; 2.7857x over previous
//
#include <hip/hip_runtime.h>
#include <cmath>

#define TT 64
#define BB 64
#define SS 512
#define AA 16
#define RR 64
#define HH 32
#define EPS 1e-6f

// ws layout in floats
#define WS_TR   0                         // transition [A][S][S] = 4194304
#define WS_AT   4194304                   // alpha_a transposed [T][A][B] = 65536
#define WS_PDF  (WS_AT + 65536)           // tau_pdf [32]
#define WS_X0   (WS_PDF + 32)             // sigma buf 0 [B][S] = 32768
#define WS_X1   (WS_X0 + 32768)           // sigma buf 1
#define WS_X2   (WS_X1 + 32768)           // sigma buf 2
#define WS_BAR  (WS_X2 + 32768)           // barrier region (1024 uints)
#define WS_G    (WS_BAR + 1024)           // Gacc [64 t][64 n] = 4096

#define AGENT __HIP_MEMORY_SCOPE_AGENT

__device__ __forceinline__ float aload(const float* p) {
  return __hip_atomic_load(p, __ATOMIC_RELAXED, AGENT);
}
__device__ __forceinline__ void astore(float* p, float v) {
  __hip_atomic_store(p, v, __ATOMIC_RELAXED, AGENT);
}

// ---------------- transition
__global__ __launch_bounds__(256) void k_trans2(const float* __restrict__ u,
                                                const float* __restrict__ v,
                                                float* __restrict__ Tr) {
  int bx = blockIdx.x;
  int k = bx >> 5, ic = bx & 31, i0 = ic * 16;
  __shared__ float urot_s[16][68];
  __shared__ float ut_s[64][68];
  __shared__ float w_s[16][516];
  int tid = threadIdx.x;
  int lane = tid & 63, wv = tid >> 6;

  float vkm = v[k*RR + lane];
  float n2 = vkm * vkm;
  #pragma unroll
  for (int o = 32; o > 0; o >>= 1) n2 += __shfl_xor(n2, o, 64);

  #pragma unroll
  for (int r = 0; r < 4; r++) {
    int il = wv*4 + r;
    float um = u[(size_t)(i0 + il)*RR + lane];
    float dt = um * vkm;
    #pragma unroll
    for (int o = 32; o > 0; o >>= 1) dt += __shfl_xor(dt, o, 64);
    urot_s[il][lane] = um - (2.f * dt / n2) * vkm;
  }

  int il = tid >> 4, jl4 = (tid & 15) * 4;
  for (int jt = 0; jt < 8; jt++) {
    __syncthreads();
    #pragma unroll
    for (int q = 0; q < 4; q++) {
      int fi = q*256 + tid;
      int r = fi >> 4, c4 = (fi & 15) * 4;
      float4 uu = *(const float4*)(u + (size_t)(jt*64 + r)*RR + c4);
      ut_s[c4+0][r] = uu.x; ut_s[c4+1][r] = uu.y;
      ut_s[c4+2][r] = uu.z; ut_s[c4+3][r] = uu.w;
    }
    __syncthreads();
    float4 acc = {0.f, 0.f, 0.f, 0.f};
    #pragma unroll 8
    for (int m = 0; m < 64; m++) {
      float ur = urot_s[il][m];
      float4 uu = *(const float4*)&ut_s[m][jl4];
      acc.x = fmaf(ur, uu.x, acc.x);
      acc.y = fmaf(ur, uu.y, acc.y);
      acc.z = fmaf(ur, uu.z, acc.z);
      acc.w = fmaf(ur, uu.w, acc.w);
    }
    *(float4*)&w_s[il][jt*64 + jl4] = acc;
  }
  __syncthreads();

  #pragma unroll
  for (int r = 0; r < 4; r++) {
    int ir = wv*4 + r;
    float vals[8]; float mx = -1e30f;
    #pragma unroll
    for (int q = 0; q < 8; q++) { vals[q] = w_s[ir][q*64 + lane]; mx = fmaxf(mx, vals[q]); }
    #pragma unroll
    for (int o = 32; o > 0; o >>= 1) mx = fmaxf(mx, __shfl_xor(mx, o, 64));
    float sm = 0.f;
    #pragma unroll
    for (int q = 0; q < 8; q++) { vals[q] = __expf(vals[q] - mx); sm += vals[q]; }
    #pragma unroll
    for (int o = 32; o > 0; o >>= 1) sm += __shfl_xor(sm, o, 64);
    float inv = 1.f / sm;
    #pragma unroll
    for (int q = 0; q < 8; q++)
      Tr[((size_t)k*SS + (i0 + ir))*SS + q*64 + lane] = vals[q] * inv;
  }
}

// ---------------- alpha_a transposed [T][A][B]
__global__ __launch_bounds__(256) void k_alpha_a(const float* __restrict__ lpu,
                                                 float* __restrict__ aT) {
  int idx = blockIdx.x*256 + threadIdx.x;
  int t = idx >> 6, n = idx & 63;
  const float* x = lpu + (size_t)idx * AA;
  float xs[AA]; float m = -1e30f;
  #pragma unroll
  for (int k = 0; k < AA; k++) { xs[k] = x[k]; m = fmaxf(m, xs[k]); }
  float s = 0.f;
  #pragma unroll
  for (int k = 0; k < AA; k++) { xs[k] = __expf(xs[k]-m); s += xs[k]; }
  float inv = 1.f/s;
  #pragma unroll
  for (int k = 0; k < AA; k++) aT[t*(AA*BB) + k*BB + n] = xs[k]*inv;
}

// ---------------- Poisson pdf
__global__ void k_taupdf(const float* __restrict__ tau, float* __restrict__ pdf) {
  __shared__ float pl[HH]; __shared__ float ss;
  int tid = threadIdx.x;
  float rate = log1pf(expf(tau[0]));
  if (tid < HH) {
    float kk = (float)(tid+1);
    pl[tid] = expf(kk*logf(rate) - rate - lgammaf(kk+1.f));
  }
  __syncthreads();
  if (tid == 0) { float s = 0.f; for (int h = 0; h < HH; h++) s += pl[h]; ss = 1.f/s; }
  __syncthreads();
  if (tid < HH) pdf[tid] = pl[tid]*ss;
}

// ---------------- zero X1/X2, barrier region, Gacc, alpha_pi
__global__ __launch_bounds__(256) void k_zero(float* __restrict__ X1,
                                              float* __restrict__ X2,
                                              unsigned* __restrict__ bar,
                                              float* __restrict__ alpha_pi,
                                              float* __restrict__ Gacc) {
  int idx = blockIdx.x*256 + threadIdx.x;   // grid 256*256 = 65536
  if (idx < 32768) { X1[idx] = 0.f; X2[idx] = 0.f; }
  if (idx < 1024) bar[idx] = 0u;
  if (idx < 4096) Gacc[idx] = 0.f;
  alpha_pi[idx] = 0.f;                      // 65536 floats
}

// ---------------- persistent scan: 256 blocks x 512 thr (proven r2 config)
// Critical-path trims vs r2: (1) per-thread invG via v_rcp (removes sync #1 and
// the LDS broadcast), (2) lpo[t] prefetched into regs during step t's GEMM and
// consumed at t+1, (3) bf hoisted out of the kb loop (32->8 ds_read_b128),
// (4) __expf. Tr slice (64 KB, time-invariant) staged in LDS once. atomicAdd
// X-rotation fan-in (16-way over ic) unchanged from r2. Normalization carried
// one step behind via scalar G[n]; alpha_b written unnormalized (k_norm fixes).
__global__ __launch_bounds__(512) void k_scan(const float* __restrict__ Tr,
                                              const float* __restrict__ aT,
                                              const float* __restrict__ lpo,
                                              const float* __restrict__ b,
                                              float* __restrict__ X0,
                                              float* __restrict__ X1,
                                              float* __restrict__ X2,
                                              float* __restrict__ alpha_b,
                                              float* __restrict__ Gacc,
                                              unsigned* __restrict__ bar) {
  __shared__ float TrL[16*32*32];  // 64 KB staged transition slice [k][i_local][j_local]
  __shared__ float bel_s[32*68];   // stride 68: 8 ii-rows hit 8 distinct bank groups
  __shared__ float a_s[16*64];
  int tid = threadIdx.x, bx = blockIdx.x;
  int jc = bx & 15, ic = bx >> 4;
  int i0 = ic*32, j0 = jc*32;
  int g = bx & 7;
  unsigned* arr = bar + g*32;
  unsigned* gcnt = bar + 256;
  unsigned* rel = bar + 288 + g*32;

  // one-time stage of Tr slice: 4096 float4, contiguous b128 writes (conflict-free)
  #pragma unroll
  for (int q = 0; q < 8; q++) {
    int f = q*512 + tid;
    int k = f >> 8, rem = f & 255;
    int i = rem >> 3, j4 = rem & 7;
    float4 tv = *(const float4*)(Tr + ((size_t)k*SS + i0 + i)*SS + j0 + j4*4);
    *(float4*)&TrL[(k*32 + i)*32 + j4*4] = tv;
  }

  int nbase = tid >> 5, il = tid & 31;     // bel mapping: q -> nn = q*16 + nbase
  float lp_pf[4];                          // prefetched lpo[t] (used at t+1)

  for (int t = 0; t < TT; t++) {
    const float* Xr; float* Xw; float* Xz;
    {
      int r = t % 3;
      if (r == 0)      { Xr = X0; Xw = X1; Xz = X2; }
      else if (r == 1) { Xr = X1; Xw = X2; Xz = X0; }
      else             { Xr = X2; Xw = X0; Xz = X1; }
    }

    // zero next-next buffer (nobody reads/writes it this step)
    { int g2 = bx*512 + tid; if (g2 < 32768) astore(Xz + g2, 0.f); }

    // bel pass: thread's 4 (nn, il) elems; per-thread invG (fast rcp), prefetched lpo
    if (t == 0) {
      #pragma unroll
      for (int q = 0; q < 4; q++) {
        int nn = q*16 + nbase;
        bel_s[il*68 + nn] = b[(size_t)nn*SS + i0 + il];
      }
    } else {
      float invG_q[4];
      if (t >= 2) {
        #pragma unroll
        for (int q = 0; q < 4; q++)
          invG_q[q] = __builtin_amdgcn_rcpf(aload(Gacc + (size_t)(t-2)*64 + q*16 + nbase));
      } else {
        #pragma unroll
        for (int q = 0; q < 4; q++) invG_q[q] = 1.0f;
      }
      #pragma unroll
      for (int q = 0; q < 4; q++) {
        int nn = q*16 + nbase;
        size_t off = (size_t)nn*SS + i0 + il;
        float val = fmaf(aload(Xr + off), invG_q[q], EPS) * __expf(lp_pf[q]);
        bel_s[il*68 + nn] = val;
        if (ic == jc) astore(alpha_b + ((size_t)(t-1)*BB + nn)*SS + i0 + il, val);
      }
    }
    if (tid < 256) *(float4*)&a_s[tid*4] = *(const float4*)(aT + (size_t)t*1024 + tid*4);
    __syncthreads();

    // prefetch lpo[t] for next step's bel pass (in flight during GEMM)
    #pragma unroll
    for (int q = 0; q < 4; q++)
      lp_pf[q] = lpo[(size_t)t*BB*SS + (size_t)(q*16 + nbase)*SS + i0 + il];

    // diagonal blocks: partial G(t-1) over this i-slice (consumed at t+1)
    if (t >= 1 && ic == jc && tid < 64) {
      float s = 0.f;
      #pragma unroll
      for (int il2 = 0; il2 < 32; il2++) s += bel_s[il2*68 + tid];
      atomicAdd(Gacc + (size_t)(t-1)*64 + tid, s);
    }

    // GEMM (all operands in LDS)
    int jq = tid & 7, ii = (tid >> 3) & 7, nq = tid >> 6;
    int n0 = nq*8;
    float4 acc[8];
    #pragma unroll
    for (int m = 0; m < 8; m++) acc[m] = make_float4(0.f, 0.f, 0.f, 0.f);
    const float* TrBase = TrL + ii*32 + jq*4;

    // bf is kb-invariant: load once (8 b128 instead of 32)
    float bf[4][8];
    #pragma unroll
    for (int io = 0; io < 4; io++) {
      *(float4*)&bf[io][0] = *(float4*)&bel_s[(io*8+ii)*68 + n0];
      *(float4*)&bf[io][4] = *(float4*)&bel_s[(io*8+ii)*68 + n0 + 4];
    }

    #pragma unroll
    for (int kb = 0; kb < 4; kb++) {
      float af[4][8];
      #pragma unroll
      for (int kk = 0; kk < 4; kk++) {
        *(float4*)&af[kk][0] = *(float4*)&a_s[(kb*4+kk)*64 + n0];
        *(float4*)&af[kk][4] = *(float4*)&a_s[(kb*4+kk)*64 + n0 + 4];
      }
      #pragma unroll
      for (int io = 0; io < 4; io++) {
        #pragma unroll
        for (int kk = 0; kk < 4; kk++) {
          float4 tv = *(const float4*)(TrBase + (kb*4+kk)*1024 + io*256);
          #pragma unroll
          for (int m = 0; m < 8; m++) {
            float w = af[kk][m] * bf[io][m];
            acc[m].x = fmaf(w, tv.x, acc[m].x);
            acc[m].y = fmaf(w, tv.y, acc[m].y);
            acc[m].z = fmaf(w, tv.z, acc[m].z);
            acc[m].w = fmaf(w, tv.w, acc[m].w);
          }
        }
      }
    }

    #pragma unroll
    for (int m = 0; m < 8; m++) {
      #pragma unroll
      for (int o = 8; o <= 32; o <<= 1) {
        acc[m].x += __shfl_xor(acc[m].x, o, 64);
        acc[m].y += __shfl_xor(acc[m].y, o, 64);
        acc[m].z += __shfl_xor(acc[m].z, o, 64);
        acc[m].w += __shfl_xor(acc[m].w, o, 64);
      }
    }
    if (ii == 0) {
      #pragma unroll
      for (int m = 0; m < 8; m++) {
        float* dst = Xw + (size_t)(n0+m)*SS + j0 + jq*4;
        atomicAdd(dst+0, acc[m].x);
        atomicAdd(dst+1, acc[m].y);
        atomicAdd(dst+2, acc[m].z);
        atomicAdd(dst+3, acc[m].w);
      }
    }

    // hierarchical barrier, epoch e = t+1 (monotonic counters, no reset)
    __syncthreads();
    if (tid == 0) {
      unsigned e = (unsigned)(t + 1);
      unsigned np = __hip_atomic_fetch_add(arr, 1u, __ATOMIC_RELEASE, AGENT);
      if (np == e*32u - 1u) {                       // last arrival of this group
        unsigned gp = __hip_atomic_fetch_add(gcnt, 1u, __ATOMIC_RELEASE, AGENT);
        if (gp == e*8u - 1u) {                      // last group: broadcast release
          #pragma unroll
          for (int g2 = 0; g2 < 8; g2++)
            __hip_atomic_store(bar + 288 + g2*32, e, __ATOMIC_RELAXED, AGENT);
        }
      }
      while (__hip_atomic_load(rel, __ATOMIC_RELAXED, AGENT) < e)
        __builtin_amdgcn_s_sleep(1);
      __atomic_signal_fence(__ATOMIC_ACQUIRE);
    }
    __syncthreads();
  }
}

// ---------------- normalize alpha_b rows t=0..62 by invG (row 63 done in k_lastbel)
__global__ __launch_bounds__(128) void k_norm(float* __restrict__ alpha_b,
                                              const float* __restrict__ Gacc) {
  int row = blockIdx.x;                 // 4032 = 63 t * 64 n
  int t = row >> 6, n = row & 63;
  float inv = 1.f / Gacc[t*64 + n];
  float4* p = (float4*)(alpha_b + ((size_t)t*BB + n)*SS);
  float4 x = p[threadIdx.x];
  x.x *= inv; x.y *= inv; x.z *= inv; x.w *= inv;
  p[threadIdx.x] = x;
}

// ---------------- final belief (t=63) from X1 (apply invG(62))
__global__ __launch_bounds__(512) void k_lastbel(const float* __restrict__ X,
                                                 const float* __restrict__ lpo,
                                                 const float* __restrict__ Gacc,
                                                 float* __restrict__ alpha_b) {
  __shared__ float red[512];
  int n = blockIdx.x, j = threadIdx.x;
  float invG = 1.f / Gacc[62*64 + n];
  size_t off = (size_t)n*SS + j;
  float gv = fmaf(X[off], invG, EPS) * __expf(lpo[((size_t)63*BB + n)*SS + j]);
  red[j] = gv; __syncthreads();
  for (int s = 256; s > 0; s >>= 1) { if (j < s) red[j] += red[j+s]; __syncthreads(); }
  float inv = 1.f / red[0];
  alpha_b[((size_t)63*BB + n)*SS + j] = gv * inv;
}

// ---------------- plan(): 512 blocks (n x hk-eighth) x 256 thr, 8t x 2hk reg tile
__global__ __launch_bounds__(256) void k_pi(const float* __restrict__ alpha_b,
                                            const float* __restrict__ value,
                                            const float* __restrict__ pdf,
                                            float* __restrict__ alpha_pi) {
  __shared__ float Ab_l[64][132];   // i-tile of 128, pad 4
  __shared__ float lg[64][68];      // logits [t][hk_local 64]
  __shared__ float pdf_l[HH];
  int tid = threadIdx.x, bx = blockIdx.x;
  int n = bx >> 3, e = bx & 7;
  if (tid < HH) pdf_l[tid] = pdf[tid];
  int hkg = tid >> 3, tg = tid & 7;
  int hk0 = e*64 + hkg*2;
  const float* V0 = value + (((size_t)(hk0    >> 4)*BB + n)*AA + (hk0     & 15))*SS;
  const float* V1 = value + (((size_t)((hk0+1) >> 4)*BB + n)*AA + ((hk0+1) & 15))*SS;

  float4 a0[8], a1[8];
  #pragma unroll
  for (int m = 0; m < 8; m++) { a0[m] = make_float4(0,0,0,0); a1[m] = make_float4(0,0,0,0); }

  for (int it = 0; it < 4; it++) {
    __syncthreads();
    #pragma unroll
    for (int q = 0; q < 8; q++) {
      int idx = q*256 + tid;
      int tt = idx >> 5, il4 = (idx & 31)*4;
      float4 ab = *(const float4*)(alpha_b + ((size_t)tt*BB + n)*SS + it*128 + il4);
      *(float4*)&Ab_l[tt][il4] = ab;
    }
    __syncthreads();
    #pragma unroll 4
    for (int iq = 0; iq < 32; iq++) {
      float4 v0 = *(const float4*)(V0 + it*128 + iq*4);
      float4 v1 = *(const float4*)(V1 + it*128 + iq*4);
      #pragma unroll
      for (int tt = 0; tt < 8; tt++) {
        float4 ab = *(const float4*)&Ab_l[tt*8 + tg][iq*4];
        a0[tt].x = fmaf(ab.x, v0.x, a0[tt].x);
        a0[tt].y = fmaf(ab.y, v0.y, a0[tt].y);
        a0[tt].z = fmaf(ab.z, v0.z, a0[tt].z);
        a0[tt].w = fmaf(ab.w, v0.w, a0[tt].w);
        a1[tt].x = fmaf(ab.x, v1.x, a1[tt].x);
        a1[tt].y = fmaf(ab.y, v1.y, a1[tt].y);
        a1[tt].z = fmaf(ab.z, v1.z, a1[tt].z);
        a1[tt].w = fmaf(ab.w, v1.w, a1[tt].w);
      }
    }
  }
  #pragma unroll
  for (int tt = 0; tt < 8; tt++) {
    lg[tt*8 + tg][hkg*2 + 0] = a0[tt].x + a0[tt].y + a0[tt].z + a0[tt].w;
    lg[tt*8 + tg][hkg*2 + 1] = a1[tt].x + a1[tt].y + a1[tt].z + a1[tt].w;
  }
  __syncthreads();

  // softmax over k for (t, local h): 64t x 4h = 256 threads
  {
    int t = tid >> 2, hh = tid & 3;
    float* row = &lg[t][hh*16];
    float m = row[0];
    #pragma unroll
    for (int k2 = 1; k2 < 16; k2++) m = fmaxf(m, row[k2]);
    float ex[16]; float s = 0.f;
    #pragma unroll
    for (int k2 = 0; k2 < 16; k2++) { ex[k2] = __expf(row[k2]-m); s += ex[k2]; }
    float w = pdf_l[e*4 + hh] / s;
    #pragma unroll
    for (int k2 = 0; k2 < 16; k2++) row[k2] = ex[k2]*w;
  }
  __syncthreads();

  // combine 4 local h and atomic into alpha_pi
  #pragma unroll
  for (int q = 0; q < 4; q++) {
    int idx = q*256 + tid;           // 1024 = 64t x 16k
    int t = idx >> 4, k2 = idx & 15;
    float s = lg[t][0*16+k2] + lg[t][1*16+k2] + lg[t][2*16+k2] + lg[t][3*16+k2];
    atomicAdd(alpha_pi + ((size_t)t*BB + n)*AA + k2, s);
  }
}

extern "C" void kernel_launch(void* const* d_in, const int* in_sizes, int n_in,
                              void* d_out, int out_size, void* d_ws, size_t ws_size,
                              hipStream_t stream) {
  const float* lpo   = (const float*)d_in[0];
  const float* lpu   = (const float*)d_in[1];
  const float* value = (const float*)d_in[2];
  const float* b     = (const float*)d_in[3];
  const float* u     = (const float*)d_in[4];
  const float* v     = (const float*)d_in[5];
  const float* tau   = (const float*)d_in[6];
  float* out = (float*)d_out;
  float* ws  = (float*)d_ws;

  float* Tr  = ws + WS_TR;
  float* aT  = ws + WS_AT;
  float* pdf = ws + WS_PDF;
  float* X0  = ws + WS_X0;
  float* X1  = ws + WS_X1;
  float* X2  = ws + WS_X2;
  unsigned* bar = (unsigned*)(ws + WS_BAR);
  float* Gacc = ws + WS_G;

  float* alpha_b  = out;
  float* alpha_pi = out + (size_t)TT*BB*SS;

  hipLaunchKernelGGL(k_trans2,  dim3(512), dim3(256), 0, stream, u, v, Tr);
  hipLaunchKernelGGL(k_alpha_a, dim3(16),  dim3(256), 0, stream, lpu, aT);
  hipLaunchKernelGGL(k_taupdf,  dim3(1),   dim3(64),  0, stream, tau, pdf);
  hipLaunchKernelGGL(k_zero,    dim3(256), dim3(256), 0, stream, X1, X2, bar, alpha_pi, Gacc);

  void* args[10];
  args[0] = (void*)&Tr;  args[1] = (void*)&aT;  args[2] = (void*)&lpo;
  args[3] = (void*)&b;   args[4] = (void*)&X0;  args[5] = (void*)&X1;
  args[6] = (void*)&X2;  args[7] = (void*)&alpha_b; args[8] = (void*)&Gacc;
  args[9] = (void*)&bar;
  hipLaunchCooperativeKernel(k_scan, dim3(256), dim3(512), args, 0, stream);

  hipLaunchKernelGGL(k_norm,    dim3(4032), dim3(128), 0, stream, alpha_b, Gacc);
  hipLaunchKernelGGL(k_lastbel, dim3(64), dim3(512), 0, stream, X1, lpo, Gacc, alpha_b);
  hipLaunchKernelGGL(k_pi, dim3(512), dim3(256), 0, stream, alpha_b, value, pdf, alpha_pi);
}

// Round 9
// 1193.764 us; speedup vs baseline: 3.0194x; 1.0839x over previous
//
#include <hip/hip_runtime.h>
#include <cmath>

#define TT 64
#define BB 64
#define SS 512
#define AA 16
#define RR 64
#define HH 32
#define EPS 1e-6f

// ws layout in floats
#define WS_TR   0                         // transition [A][S][S] = 4194304
#define WS_AT   4194304                   // alpha_a transposed [T][A][B] = 65536
#define WS_PDF  (WS_AT + 65536)           // tau_pdf [32]
#define WS_X0   (WS_PDF + 32)             // sigma buf 0 [B][S] = 32768
#define WS_X1   (WS_X0 + 32768)           // sigma buf 1
#define WS_X2   (WS_X1 + 32768)           // sigma buf 2
#define WS_BAR  (WS_X2 + 32768)           // barrier region (1024 uints)
#define WS_G    (WS_BAR + 1024)           // Gacc [64 t][64 n] = 4096

#define AGENT __HIP_MEMORY_SCOPE_AGENT

__device__ __forceinline__ float aload(const float* p) {
  return __hip_atomic_load(p, __ATOMIC_RELAXED, AGENT);
}
__device__ __forceinline__ void astore(float* p, float v) {
  __hip_atomic_store(p, v, __ATOMIC_RELAXED, AGENT);
}

// ---------------- transition
__global__ __launch_bounds__(256) void k_trans2(const float* __restrict__ u,
                                                const float* __restrict__ v,
                                                float* __restrict__ Tr) {
  int bx = blockIdx.x;
  int k = bx >> 5, ic = bx & 31, i0 = ic * 16;
  __shared__ float urot_s[16][68];
  __shared__ float ut_s[64][68];
  __shared__ float w_s[16][516];
  int tid = threadIdx.x;
  int lane = tid & 63, wv = tid >> 6;

  float vkm = v[k*RR + lane];
  float n2 = vkm * vkm;
  #pragma unroll
  for (int o = 32; o > 0; o >>= 1) n2 += __shfl_xor(n2, o, 64);

  #pragma unroll
  for (int r = 0; r < 4; r++) {
    int il = wv*4 + r;
    float um = u[(size_t)(i0 + il)*RR + lane];
    float dt = um * vkm;
    #pragma unroll
    for (int o = 32; o > 0; o >>= 1) dt += __shfl_xor(dt, o, 64);
    urot_s[il][lane] = um - (2.f * dt / n2) * vkm;
  }

  int il = tid >> 4, jl4 = (tid & 15) * 4;
  for (int jt = 0; jt < 8; jt++) {
    __syncthreads();
    #pragma unroll
    for (int q = 0; q < 4; q++) {
      int fi = q*256 + tid;
      int r = fi >> 4, c4 = (fi & 15) * 4;
      float4 uu = *(const float4*)(u + (size_t)(jt*64 + r)*RR + c4);
      ut_s[c4+0][r] = uu.x; ut_s[c4+1][r] = uu.y;
      ut_s[c4+2][r] = uu.z; ut_s[c4+3][r] = uu.w;
    }
    __syncthreads();
    float4 acc = {0.f, 0.f, 0.f, 0.f};
    #pragma unroll 8
    for (int m = 0; m < 64; m++) {
      float ur = urot_s[il][m];
      float4 uu = *(const float4*)&ut_s[m][jl4];
      acc.x = fmaf(ur, uu.x, acc.x);
      acc.y = fmaf(ur, uu.y, acc.y);
      acc.z = fmaf(ur, uu.z, acc.z);
      acc.w = fmaf(ur, uu.w, acc.w);
    }
    *(float4*)&w_s[il][jt*64 + jl4] = acc;
  }
  __syncthreads();

  #pragma unroll
  for (int r = 0; r < 4; r++) {
    int ir = wv*4 + r;
    float vals[8]; float mx = -1e30f;
    #pragma unroll
    for (int q = 0; q < 8; q++) { vals[q] = w_s[ir][q*64 + lane]; mx = fmaxf(mx, vals[q]); }
    #pragma unroll
    for (int o = 32; o > 0; o >>= 1) mx = fmaxf(mx, __shfl_xor(mx, o, 64));
    float sm = 0.f;
    #pragma unroll
    for (int q = 0; q < 8; q++) { vals[q] = __expf(vals[q] - mx); sm += vals[q]; }
    #pragma unroll
    for (int o = 32; o > 0; o >>= 1) sm += __shfl_xor(sm, o, 64);
    float inv = 1.f / sm;
    #pragma unroll
    for (int q = 0; q < 8; q++)
      Tr[((size_t)k*SS + (i0 + ir))*SS + q*64 + lane] = vals[q] * inv;
  }
}

// ---------------- alpha_a transposed [T][A][B]
__global__ __launch_bounds__(256) void k_alpha_a(const float* __restrict__ lpu,
                                                 float* __restrict__ aT) {
  int idx = blockIdx.x*256 + threadIdx.x;
  int t = idx >> 6, n = idx & 63;
  const float* x = lpu + (size_t)idx * AA;
  float xs[AA]; float m = -1e30f;
  #pragma unroll
  for (int k = 0; k < AA; k++) { xs[k] = x[k]; m = fmaxf(m, xs[k]); }
  float s = 0.f;
  #pragma unroll
  for (int k = 0; k < AA; k++) { xs[k] = __expf(xs[k]-m); s += xs[k]; }
  float inv = 1.f/s;
  #pragma unroll
  for (int k = 0; k < AA; k++) aT[t*(AA*BB) + k*BB + n] = xs[k]*inv;
}

// ---------------- Poisson pdf
__global__ void k_taupdf(const float* __restrict__ tau, float* __restrict__ pdf) {
  __shared__ float pl[HH]; __shared__ float ss;
  int tid = threadIdx.x;
  float rate = log1pf(expf(tau[0]));
  if (tid < HH) {
    float kk = (float)(tid+1);
    pl[tid] = expf(kk*logf(rate) - rate - lgammaf(kk+1.f));
  }
  __syncthreads();
  if (tid == 0) { float s = 0.f; for (int h = 0; h < HH; h++) s += pl[h]; ss = 1.f/s; }
  __syncthreads();
  if (tid < HH) pdf[tid] = pl[tid]*ss;
}

// ---------------- zero X1/X2, barrier region, Gacc, alpha_pi
__global__ __launch_bounds__(256) void k_zero(float* __restrict__ X1,
                                              float* __restrict__ X2,
                                              unsigned* __restrict__ bar,
                                              float* __restrict__ alpha_pi,
                                              float* __restrict__ Gacc) {
  int idx = blockIdx.x*256 + threadIdx.x;   // grid 256*256 = 65536
  if (idx < 32768) { X1[idx] = 0.f; X2[idx] = 0.f; }
  if (idx < 1024) bar[idx] = 0u;
  if (idx < 4096) Gacc[idx] = 0.f;
  alpha_pi[idx] = 0.f;                      // 65536 floats
}

// ---------------- persistent scan: 256 blocks x 512 thr, hierarchical barrier
// EXACT r2 structure (verified 1070 us): Tr slice (64 KB, time-invariant) in
// LDS; invG via 64-thread LDS broadcast; atomicAdd 3-buffer X rotation.
// Only change: expf -> __expf in the bel pass (accuracy verified nil in r8).
// Normalization carried one step behind via scalar G[n] (GEMM linear in bel):
//   S(t) = GEMM(g(t-1)),  g(t) = (S(t)*invG(t-1) + eps)*exp(lpo(t)),  G(t) = sum_j g(t)
// alpha_b written UNNORMALIZED here; k_norm scales rows afterwards.
__global__ __launch_bounds__(512) void k_scan(const float* __restrict__ Tr,
                                              const float* __restrict__ aT,
                                              const float* __restrict__ lpo,
                                              const float* __restrict__ b,
                                              float* __restrict__ X0,
                                              float* __restrict__ X1,
                                              float* __restrict__ X2,
                                              float* __restrict__ alpha_b,
                                              float* __restrict__ Gacc,
                                              unsigned* __restrict__ bar) {
  __shared__ float TrL[16*32*32];  // 64 KB staged transition slice [k][i_local][j_local]
  __shared__ float bel_s[32*68];   // stride 68: 8 ii-rows hit 8 distinct bank groups
  __shared__ float a_s[16*64];
  __shared__ float invG_l[64];
  int tid = threadIdx.x, bx = blockIdx.x;
  int jc = bx & 15, ic = bx >> 4;
  int i0 = ic*32, j0 = jc*32;
  int g = bx & 7;
  unsigned* arr = bar + g*32;
  unsigned* gcnt = bar + 256;
  unsigned* rel = bar + 288 + g*32;

  // one-time stage of Tr slice: 4096 float4, contiguous b128 writes (conflict-free)
  #pragma unroll
  for (int q = 0; q < 8; q++) {
    int f = q*512 + tid;
    int k = f >> 8, rem = f & 255;
    int i = rem >> 3, j4 = rem & 7;
    float4 tv = *(const float4*)(Tr + ((size_t)k*SS + i0 + i)*SS + j0 + j4*4);
    *(float4*)&TrL[(k*32 + i)*32 + j4*4] = tv;
  }
  __syncthreads();

  for (int t = 0; t < TT; t++) {
    const float* Xr; float* Xw; float* Xz;
    {
      int r = t % 3;
      if (r == 0)      { Xr = X0; Xw = X1; Xz = X2; }
      else if (r == 1) { Xr = X1; Xw = X2; Xz = X0; }
      else             { Xr = X2; Xw = X0; Xz = X1; }
    }
    const float* lpoPrev = lpo + (size_t)(t-1)*BB*SS;

    // zero next-next buffer (nobody reads/writes it this step)
    { int g2 = bx*512 + tid; if (g2 < 32768) astore(Xz + g2, 0.f); }

    // invG (scalar per n) from two steps back; 1.0 for t<2
    if (tid < 64)
      invG_l[tid] = (t >= 2) ? 1.f / aload(Gacc + (size_t)(t-2)*64 + tid) : 1.0f;
    __syncthreads();

    // bel pass: bel_s slice (unnormalized g) + a_s stage (+ alpha_b[t-1] on diagonal)
    if (t == 0) {
      #pragma unroll
      for (int q = 0; q < 4; q++) {
        int idx = q*512 + tid;
        int nn = idx >> 5, il = idx & 31;
        bel_s[il*68 + nn] = b[(size_t)nn*SS + i0 + il];
      }
    } else {
      #pragma unroll
      for (int q = 0; q < 4; q++) {
        int idx = q*512 + tid;
        int nn = idx >> 5, il = idx & 31;
        size_t off = (size_t)nn*SS + i0 + il;
        float val = fmaf(aload(Xr + off), invG_l[nn], EPS) * __expf(lpoPrev[off]);
        bel_s[il*68 + nn] = val;
        if (ic == jc) astore(alpha_b + ((size_t)(t-1)*BB + nn)*SS + i0 + il, val);
      }
    }
    if (tid < 256) *(float4*)&a_s[tid*4] = *(const float4*)(aT + (size_t)t*1024 + tid*4);
    __syncthreads();

    // diagonal blocks: partial G(t-1) over this i-slice (consumed at t+1)
    if (t >= 1 && ic == jc && tid < 64) {
      float s = 0.f;
      #pragma unroll
      for (int il = 0; il < 32; il++) s += bel_s[il*68 + tid];
      atomicAdd(Gacc + (size_t)(t-1)*64 + tid, s);
    }

    // GEMM (all operands in LDS)
    int jq = tid & 7, ii = (tid >> 3) & 7, nq = tid >> 6;
    int n0 = nq*8;
    float4 acc[8];
    #pragma unroll
    for (int m = 0; m < 8; m++) acc[m] = make_float4(0.f, 0.f, 0.f, 0.f);
    const float* TrBase = TrL + ii*32 + jq*4;

    for (int kb = 0; kb < 4; kb++) {
      float af[4][8];
      #pragma unroll
      for (int kk = 0; kk < 4; kk++) {
        *(float4*)&af[kk][0] = *(float4*)&a_s[(kb*4+kk)*64 + n0];
        *(float4*)&af[kk][4] = *(float4*)&a_s[(kb*4+kk)*64 + n0 + 4];
      }
      #pragma unroll
      for (int io = 0; io < 4; io++) {
        float bf[8];
        *(float4*)&bf[0] = *(float4*)&bel_s[(io*8+ii)*68 + n0];
        *(float4*)&bf[4] = *(float4*)&bel_s[(io*8+ii)*68 + n0 + 4];
        #pragma unroll
        for (int kk = 0; kk < 4; kk++) {
          float4 tv = *(const float4*)(TrBase + (kb*4+kk)*1024 + io*256);
          #pragma unroll
          for (int m = 0; m < 8; m++) {
            float w = af[kk][m] * bf[m];
            acc[m].x = fmaf(w, tv.x, acc[m].x);
            acc[m].y = fmaf(w, tv.y, acc[m].y);
            acc[m].z = fmaf(w, tv.z, acc[m].z);
            acc[m].w = fmaf(w, tv.w, acc[m].w);
          }
        }
      }
    }

    #pragma unroll
    for (int m = 0; m < 8; m++) {
      #pragma unroll
      for (int o = 8; o <= 32; o <<= 1) {
        acc[m].x += __shfl_xor(acc[m].x, o, 64);
        acc[m].y += __shfl_xor(acc[m].y, o, 64);
        acc[m].z += __shfl_xor(acc[m].z, o, 64);
        acc[m].w += __shfl_xor(acc[m].w, o, 64);
      }
    }
    if (ii == 0) {
      #pragma unroll
      for (int m = 0; m < 8; m++) {
        float* dst = Xw + (size_t)(n0+m)*SS + j0 + jq*4;
        atomicAdd(dst+0, acc[m].x);
        atomicAdd(dst+1, acc[m].y);
        atomicAdd(dst+2, acc[m].z);
        atomicAdd(dst+3, acc[m].w);
      }
    }

    // hierarchical barrier, epoch e = t+1 (monotonic counters, no reset)
    __syncthreads();
    if (tid == 0) {
      unsigned e = (unsigned)(t + 1);
      unsigned np = __hip_atomic_fetch_add(arr, 1u, __ATOMIC_RELEASE, AGENT);
      if (np == e*32u - 1u) {                       // last arrival of this group
        unsigned gp = __hip_atomic_fetch_add(gcnt, 1u, __ATOMIC_RELEASE, AGENT);
        if (gp == e*8u - 1u) {                      // last group: broadcast release
          #pragma unroll
          for (int g2 = 0; g2 < 8; g2++)
            __hip_atomic_store(bar + 288 + g2*32, e, __ATOMIC_RELAXED, AGENT);
        }
      }
      while (__hip_atomic_load(rel, __ATOMIC_RELAXED, AGENT) < e)
        __builtin_amdgcn_s_sleep(1);
      __atomic_signal_fence(__ATOMIC_ACQUIRE);
    }
    __syncthreads();
  }
}

// ---------------- normalize alpha_b rows t=0..62 by invG (row 63 done in k_lastbel)
__global__ __launch_bounds__(128) void k_norm(float* __restrict__ alpha_b,
                                              const float* __restrict__ Gacc) {
  int row = blockIdx.x;                 // 4032 = 63 t * 64 n
  int t = row >> 6, n = row & 63;
  float inv = 1.f / Gacc[t*64 + n];
  float4* p = (float4*)(alpha_b + ((size_t)t*BB + n)*SS);
  float4 x = p[threadIdx.x];
  x.x *= inv; x.y *= inv; x.z *= inv; x.w *= inv;
  p[threadIdx.x] = x;
}

// ---------------- final belief (t=63) from X1 (apply invG(62))
__global__ __launch_bounds__(512) void k_lastbel(const float* __restrict__ X,
                                                 const float* __restrict__ lpo,
                                                 const float* __restrict__ Gacc,
                                                 float* __restrict__ alpha_b) {
  __shared__ float red[512];
  int n = blockIdx.x, j = threadIdx.x;
  float invG = 1.f / Gacc[62*64 + n];
  size_t off = (size_t)n*SS + j;
  float gv = fmaf(X[off], invG, EPS) * __expf(lpo[((size_t)63*BB + n)*SS + j]);
  red[j] = gv; __syncthreads();
  for (int s = 256; s > 0; s >>= 1) { if (j < s) red[j] += red[j+s]; __syncthreads(); }
  float inv = 1.f / red[0];
  alpha_b[((size_t)63*BB + n)*SS + j] = gv * inv;
}

// ---------------- plan(): 512 blocks (n x hk-eighth) x 256 thr, 8t x 2hk reg tile
__global__ __launch_bounds__(256) void k_pi(const float* __restrict__ alpha_b,
                                            const float* __restrict__ value,
                                            const float* __restrict__ pdf,
                                            float* __restrict__ alpha_pi) {
  __shared__ float Ab_l[64][132];   // i-tile of 128, pad 4
  __shared__ float lg[64][68];      // logits [t][hk_local 64]
  __shared__ float pdf_l[HH];
  int tid = threadIdx.x, bx = blockIdx.x;
  int n = bx >> 3, e = bx & 7;
  if (tid < HH) pdf_l[tid] = pdf[tid];
  int hkg = tid >> 3, tg = tid & 7;
  int hk0 = e*64 + hkg*2;
  const float* V0 = value + (((size_t)(hk0    >> 4)*BB + n)*AA + (hk0     & 15))*SS;
  const float* V1 = value + (((size_t)((hk0+1) >> 4)*BB + n)*AA + ((hk0+1) & 15))*SS;

  float4 a0[8], a1[8];
  #pragma unroll
  for (int m = 0; m < 8; m++) { a0[m] = make_float4(0,0,0,0); a1[m] = make_float4(0,0,0,0); }

  for (int it = 0; it < 4; it++) {
    __syncthreads();
    #pragma unroll
    for (int q = 0; q < 8; q++) {
      int idx = q*256 + tid;
      int tt = idx >> 5, il4 = (idx & 31)*4;
      float4 ab = *(const float4*)(alpha_b + ((size_t)tt*BB + n)*SS + it*128 + il4);
      *(float4*)&Ab_l[tt][il4] = ab;
    }
    __syncthreads();
    #pragma unroll 4
    for (int iq = 0; iq < 32; iq++) {
      float4 v0 = *(const float4*)(V0 + it*128 + iq*4);
      float4 v1 = *(const float4*)(V1 + it*128 + iq*4);
      #pragma unroll
      for (int tt = 0; tt < 8; tt++) {
        float4 ab = *(const float4*)&Ab_l[tt*8 + tg][iq*4];
        a0[tt].x = fmaf(ab.x, v0.x, a0[tt].x);
        a0[tt].y = fmaf(ab.y, v0.y, a0[tt].y);
        a0[tt].z = fmaf(ab.z, v0.z, a0[tt].z);
        a0[tt].w = fmaf(ab.w, v0.w, a0[tt].w);
        a1[tt].x = fmaf(ab.x, v1.x, a1[tt].x);
        a1[tt].y = fmaf(ab.y, v1.y, a1[tt].y);
        a1[tt].z = fmaf(ab.z, v1.z, a1[tt].z);
        a1[tt].w = fmaf(ab.w, v1.w, a1[tt].w);
      }
    }
  }
  #pragma unroll
  for (int tt = 0; tt < 8; tt++) {
    lg[tt*8 + tg][hkg*2 + 0] = a0[tt].x + a0[tt].y + a0[tt].z + a0[tt].w;
    lg[tt*8 + tg][hkg*2 + 1] = a1[tt].x + a1[tt].y + a1[tt].z + a1[tt].w;
  }
  __syncthreads();

  // softmax over k for (t, local h): 64t x 4h = 256 threads
  {
    int t = tid >> 2, hh = tid & 3;
    float* row = &lg[t][hh*16];
    float m = row[0];
    #pragma unroll
    for (int k2 = 1; k2 < 16; k2++) m = fmaxf(m, row[k2]);
    float ex[16]; float s = 0.f;
    #pragma unroll
    for (int k2 = 0; k2 < 16; k2++) { ex[k2] = __expf(row[k2]-m); s += ex[k2]; }
    float w = pdf_l[e*4 + hh] / s;
    #pragma unroll
    for (int k2 = 0; k2 < 16; k2++) row[k2] = ex[k2]*w;
  }
  __syncthreads();

  // combine 4 local h and atomic into alpha_pi
  #pragma unroll
  for (int q = 0; q < 4; q++) {
    int idx = q*256 + tid;           // 1024 = 64t x 16k
    int t = idx >> 4, k2 = idx & 15;
    float s = lg[t][0*16+k2] + lg[t][1*16+k2] + lg[t][2*16+k2] + lg[t][3*16+k2];
    atomicAdd(alpha_pi + ((size_t)t*BB + n)*AA + k2, s);
  }
}

extern "C" void kernel_launch(void* const* d_in, const int* in_sizes, int n_in,
                              void* d_out, int out_size, void* d_ws, size_t ws_size,
                              hipStream_t stream) {
  const float* lpo   = (const float*)d_in[0];
  const float* lpu   = (const float*)d_in[1];
  const float* value = (const float*)d_in[2];
  const float* b     = (const float*)d_in[3];
  const float* u     = (const float*)d_in[4];
  const float* v     = (const float*)d_in[5];
  const float* tau   = (const float*)d_in[6];
  float* out = (float*)d_out;
  float* ws  = (float*)d_ws;

  float* Tr  = ws + WS_TR;
  float* aT  = ws + WS_AT;
  float* pdf = ws + WS_PDF;
  float* X0  = ws + WS_X0;
  float* X1  = ws + WS_X1;
  float* X2  = ws + WS_X2;
  unsigned* bar = (unsigned*)(ws + WS_BAR);
  float* Gacc = ws + WS_G;

  float* alpha_b  = out;
  float* alpha_pi = out + (size_t)TT*BB*SS;

  hipLaunchKernelGGL(k_trans2,  dim3(512), dim3(256), 0, stream, u, v, Tr);
  hipLaunchKernelGGL(k_alpha_a, dim3(16),  dim3(256), 0, stream, lpu, aT);
  hipLaunchKernelGGL(k_taupdf,  dim3(1),   dim3(64),  0, stream, tau, pdf);
  hipLaunchKernelGGL(k_zero,    dim3(256), dim3(256), 0, stream, X1, X2, bar, alpha_pi, Gacc);

  void* args[10];
  args[0] = (void*)&Tr;  args[1] = (void*)&aT;  args[2] = (void*)&lpo;
  args[3] = (void*)&b;   args[4] = (void*)&X0;  args[5] = (void*)&X1;
  args[6] = (void*)&X2;  args[7] = (void*)&alpha_b; args[8] = (void*)&Gacc;
  args[9] = (void*)&bar;
  hipLaunchCooperativeKernel(k_scan, dim3(256), dim3(512), args, 0, stream);

  hipLaunchKernelGGL(k_norm,    dim3(4032), dim3(128), 0, stream, alpha_b, Gacc);
  hipLaunchKernelGGL(k_lastbel, dim3(64), dim3(512), 0, stream, X1, lpo, Gacc, alpha_b);
  hipLaunchKernelGGL(k_pi, dim3(512), dim3(256), 0, stream, alpha_b, value, pdf, alpha_pi);
}

// Round 11
// 1187.243 us; speedup vs baseline: 3.0360x; 1.0055x over previous
//
#include <hip/hip_runtime.h>
#include <cmath>

#define TT 64
#define BB 64
#define SS 512
#define AA 16
#define RR 64
#define HH 32
#define EPS 1e-6f

// ws layout in floats
#define WS_TR   0                         // transition [A][S][S] = 4194304
#define WS_AT   4194304                   // alpha_a transposed [T][A][B] = 65536
#define WS_PDF  (WS_AT + 65536)           // tau_pdf [32]
#define WS_X0   (WS_PDF + 32)             // sigma buf 0 [B][S] = 32768
#define WS_X1   (WS_X0 + 32768)           // sigma buf 1
#define WS_X2   (WS_X1 + 32768)           // sigma buf 2
#define WS_BAR  (WS_X2 + 32768)           // barrier region (1024 uints)
#define WS_G    (WS_BAR + 1024)           // Gacc [64 t][64 n] = 4096

#define AGENT __HIP_MEMORY_SCOPE_AGENT

__device__ __forceinline__ float aload(const float* p) {
  return __hip_atomic_load(p, __ATOMIC_RELAXED, AGENT);
}
__device__ __forceinline__ void astore(float* p, float v) {
  __hip_atomic_store(p, v, __ATOMIC_RELAXED, AGENT);
}

// ---------------- transition
__global__ __launch_bounds__(256) void k_trans2(const float* __restrict__ u,
                                                const float* __restrict__ v,
                                                float* __restrict__ Tr) {
  int bx = blockIdx.x;
  int k = bx >> 5, ic = bx & 31, i0 = ic * 16;
  __shared__ float urot_s[16][68];
  __shared__ float ut_s[64][68];
  __shared__ float w_s[16][516];
  int tid = threadIdx.x;
  int lane = tid & 63, wv = tid >> 6;

  float vkm = v[k*RR + lane];
  float n2 = vkm * vkm;
  #pragma unroll
  for (int o = 32; o > 0; o >>= 1) n2 += __shfl_xor(n2, o, 64);

  #pragma unroll
  for (int r = 0; r < 4; r++) {
    int il = wv*4 + r;
    float um = u[(size_t)(i0 + il)*RR + lane];
    float dt = um * vkm;
    #pragma unroll
    for (int o = 32; o > 0; o >>= 1) dt += __shfl_xor(dt, o, 64);
    urot_s[il][lane] = um - (2.f * dt / n2) * vkm;
  }

  int il = tid >> 4, jl4 = (tid & 15) * 4;
  for (int jt = 0; jt < 8; jt++) {
    __syncthreads();
    #pragma unroll
    for (int q = 0; q < 4; q++) {
      int fi = q*256 + tid;
      int r = fi >> 4, c4 = (fi & 15) * 4;
      float4 uu = *(const float4*)(u + (size_t)(jt*64 + r)*RR + c4);
      ut_s[c4+0][r] = uu.x; ut_s[c4+1][r] = uu.y;
      ut_s[c4+2][r] = uu.z; ut_s[c4+3][r] = uu.w;
    }
    __syncthreads();
    float4 acc = {0.f, 0.f, 0.f, 0.f};
    #pragma unroll 8
    for (int m = 0; m < 64; m++) {
      float ur = urot_s[il][m];
      float4 uu = *(const float4*)&ut_s[m][jl4];
      acc.x = fmaf(ur, uu.x, acc.x);
      acc.y = fmaf(ur, uu.y, acc.y);
      acc.z = fmaf(ur, uu.z, acc.z);
      acc.w = fmaf(ur, uu.w, acc.w);
    }
    *(float4*)&w_s[il][jt*64 + jl4] = acc;
  }
  __syncthreads();

  #pragma unroll
  for (int r = 0; r < 4; r++) {
    int ir = wv*4 + r;
    float vals[8]; float mx = -1e30f;
    #pragma unroll
    for (int q = 0; q < 8; q++) { vals[q] = w_s[ir][q*64 + lane]; mx = fmaxf(mx, vals[q]); }
    #pragma unroll
    for (int o = 32; o > 0; o >>= 1) mx = fmaxf(mx, __shfl_xor(mx, o, 64));
    float sm = 0.f;
    #pragma unroll
    for (int q = 0; q < 8; q++) { vals[q] = __expf(vals[q] - mx); sm += vals[q]; }
    #pragma unroll
    for (int o = 32; o > 0; o >>= 1) sm += __shfl_xor(sm, o, 64);
    float inv = 1.f / sm;
    #pragma unroll
    for (int q = 0; q < 8; q++)
      Tr[((size_t)k*SS + (i0 + ir))*SS + q*64 + lane] = vals[q] * inv;
  }
}

// ---------------- alpha_a transposed [T][A][B]
__global__ __launch_bounds__(256) void k_alpha_a(const float* __restrict__ lpu,
                                                 float* __restrict__ aT) {
  int idx = blockIdx.x*256 + threadIdx.x;
  int t = idx >> 6, n = idx & 63;
  const float* x = lpu + (size_t)idx * AA;
  float xs[AA]; float m = -1e30f;
  #pragma unroll
  for (int k = 0; k < AA; k++) { xs[k] = x[k]; m = fmaxf(m, xs[k]); }
  float s = 0.f;
  #pragma unroll
  for (int k = 0; k < AA; k++) { xs[k] = __expf(xs[k]-m); s += xs[k]; }
  float inv = 1.f/s;
  #pragma unroll
  for (int k = 0; k < AA; k++) aT[t*(AA*BB) + k*BB + n] = xs[k]*inv;
}

// ---------------- Poisson pdf
__global__ void k_taupdf(const float* __restrict__ tau, float* __restrict__ pdf) {
  __shared__ float pl[HH]; __shared__ float ss;
  int tid = threadIdx.x;
  float rate = log1pf(expf(tau[0]));
  if (tid < HH) {
    float kk = (float)(tid+1);
    pl[tid] = expf(kk*logf(rate) - rate - lgammaf(kk+1.f));
  }
  __syncthreads();
  if (tid == 0) { float s = 0.f; for (int h = 0; h < HH; h++) s += pl[h]; ss = 1.f/s; }
  __syncthreads();
  if (tid < HH) pdf[tid] = pl[tid]*ss;
}

// ---------------- zero X1/X2, barrier region, Gacc, alpha_pi
__global__ __launch_bounds__(256) void k_zero(float* __restrict__ X1,
                                              float* __restrict__ X2,
                                              unsigned* __restrict__ bar,
                                              float* __restrict__ alpha_pi,
                                              float* __restrict__ Gacc) {
  int idx = blockIdx.x*256 + threadIdx.x;   // grid 256*256 = 65536
  if (idx < 32768) { X1[idx] = 0.f; X2[idx] = 0.f; }
  if (idx < 1024) bar[idx] = 0u;
  if (idx < 4096) Gacc[idx] = 0.f;
  alpha_pi[idx] = 0.f;                      // 65536 floats
}

// ---------------- persistent scan: 256 blocks x 512 thr, hierarchical barrier
// r9 structure (verified 1072 us) + two isolated trims from the r8 bundle
// (bundle's regression was attributed to per-thread invG, NOT these):
//   (a) bf hoisted out of the kb loop: kb-invariant, 32 -> 8 ds_read_b128
//   (b) lpo[t] prefetched into regs during step t's GEMM, consumed at t+1
// invG stays as the proven 64-thread LDS broadcast. Normalization carried one
// step behind via scalar G[n]; alpha_b written unnormalized (k_norm fixes).
__global__ __launch_bounds__(512) void k_scan(const float* __restrict__ Tr,
                                              const float* __restrict__ aT,
                                              const float* __restrict__ lpo,
                                              const float* __restrict__ b,
                                              float* __restrict__ X0,
                                              float* __restrict__ X1,
                                              float* __restrict__ X2,
                                              float* __restrict__ alpha_b,
                                              float* __restrict__ Gacc,
                                              unsigned* __restrict__ bar) {
  __shared__ float TrL[16*32*32];  // 64 KB staged transition slice [k][i_local][j_local]
  __shared__ float bel_s[32*68];   // stride 68: 8 ii-rows hit 8 distinct bank groups
  __shared__ float a_s[16*64];
  __shared__ float invG_l[64];
  int tid = threadIdx.x, bx = blockIdx.x;
  int jc = bx & 15, ic = bx >> 4;
  int i0 = ic*32, j0 = jc*32;
  int g = bx & 7;
  unsigned* arr = bar + g*32;
  unsigned* gcnt = bar + 256;
  unsigned* rel = bar + 288 + g*32;

  // one-time stage of Tr slice: 4096 float4, contiguous b128 writes (conflict-free)
  #pragma unroll
  for (int q = 0; q < 8; q++) {
    int f = q*512 + tid;
    int k = f >> 8, rem = f & 255;
    int i = rem >> 3, j4 = rem & 7;
    float4 tv = *(const float4*)(Tr + ((size_t)k*SS + i0 + i)*SS + j0 + j4*4);
    *(float4*)&TrL[(k*32 + i)*32 + j4*4] = tv;
  }
  __syncthreads();

  float lp_pf[4];                  // prefetched lpo[t] (consumed at t+1)

  for (int t = 0; t < TT; t++) {
    const float* Xr; float* Xw; float* Xz;
    {
      int r = t % 3;
      if (r == 0)      { Xr = X0; Xw = X1; Xz = X2; }
      else if (r == 1) { Xr = X1; Xw = X2; Xz = X0; }
      else             { Xr = X2; Xw = X0; Xz = X1; }
    }

    // zero next-next buffer (nobody reads/writes it this step)
    { int g2 = bx*512 + tid; if (g2 < 32768) astore(Xz + g2, 0.f); }

    // invG (scalar per n) from two steps back; 1.0 for t<2
    if (tid < 64)
      invG_l[tid] = (t >= 2) ? 1.f / aload(Gacc + (size_t)(t-2)*64 + tid) : 1.0f;
    __syncthreads();

    // bel pass: bel_s slice (unnormalized g), lpo from prefetch regs
    if (t == 0) {
      #pragma unroll
      for (int q = 0; q < 4; q++) {
        int idx = q*512 + tid;
        int nn = idx >> 5, il = idx & 31;
        bel_s[il*68 + nn] = b[(size_t)nn*SS + i0 + il];
      }
    } else {
      #pragma unroll
      for (int q = 0; q < 4; q++) {
        int idx = q*512 + tid;
        int nn = idx >> 5, il = idx & 31;
        size_t off = (size_t)nn*SS + i0 + il;
        float val = fmaf(aload(Xr + off), invG_l[nn], EPS) * __expf(lp_pf[q]);
        bel_s[il*68 + nn] = val;
        if (ic == jc) astore(alpha_b + ((size_t)(t-1)*BB + nn)*SS + i0 + il, val);
      }
    }
    if (tid < 256) *(float4*)&a_s[tid*4] = *(const float4*)(aT + (size_t)t*1024 + tid*4);
    __syncthreads();

    // prefetch lpo[t] for next step's bel pass (in flight during GEMM)
    #pragma unroll
    for (int q = 0; q < 4; q++) {
      int idx = q*512 + tid;
      int nn = idx >> 5, il = idx & 31;
      lp_pf[q] = lpo[(size_t)t*BB*SS + (size_t)nn*SS + i0 + il];
    }

    // diagonal blocks: partial G(t-1) over this i-slice (consumed at t+1)
    if (t >= 1 && ic == jc && tid < 64) {
      float s = 0.f;
      #pragma unroll
      for (int il = 0; il < 32; il++) s += bel_s[il*68 + tid];
      atomicAdd(Gacc + (size_t)(t-1)*64 + tid, s);
    }

    // GEMM (all operands in LDS)
    int jq = tid & 7, ii = (tid >> 3) & 7, nq = tid >> 6;
    int n0 = nq*8;
    float4 acc[8];
    #pragma unroll
    for (int m = 0; m < 8; m++) acc[m] = make_float4(0.f, 0.f, 0.f, 0.f);
    const float* TrBase = TrL + ii*32 + jq*4;

    // bf is kb-invariant: load once (8 b128 instead of 32)
    float bf[4][8];
    #pragma unroll
    for (int io = 0; io < 4; io++) {
      *(float4*)&bf[io][0] = *(float4*)&bel_s[(io*8+ii)*68 + n0];
      *(float4*)&bf[io][4] = *(float4*)&bel_s[(io*8+ii)*68 + n0 + 4];
    }

    for (int kb = 0; kb < 4; kb++) {
      float af[4][8];
      #pragma unroll
      for (int kk = 0; kk < 4; kk++) {
        *(float4*)&af[kk][0] = *(float4*)&a_s[(kb*4+kk)*64 + n0];
        *(float4*)&af[kk][4] = *(float4*)&a_s[(kb*4+kk)*64 + n0 + 4];
      }
      #pragma unroll
      for (int io = 0; io < 4; io++) {
        #pragma unroll
        for (int kk = 0; kk < 4; kk++) {
          float4 tv = *(const float4*)(TrBase + (kb*4+kk)*1024 + io*256);
          #pragma unroll
          for (int m = 0; m < 8; m++) {
            float w = af[kk][m] * bf[io][m];
            acc[m].x = fmaf(w, tv.x, acc[m].x);
            acc[m].y = fmaf(w, tv.y, acc[m].y);
            acc[m].z = fmaf(w, tv.z, acc[m].z);
            acc[m].w = fmaf(w, tv.w, acc[m].w);
          }
        }
      }
    }

    #pragma unroll
    for (int m = 0; m < 8; m++) {
      #pragma unroll
      for (int o = 8; o <= 32; o <<= 1) {
        acc[m].x += __shfl_xor(acc[m].x, o, 64);
        acc[m].y += __shfl_xor(acc[m].y, o, 64);
        acc[m].z += __shfl_xor(acc[m].z, o, 64);
        acc[m].w += __shfl_xor(acc[m].w, o, 64);
      }
    }
    if (ii == 0) {
      #pragma unroll
      for (int m = 0; m < 8; m++) {
        float* dst = Xw + (size_t)(n0+m)*SS + j0 + jq*4;
        atomicAdd(dst+0, acc[m].x);
        atomicAdd(dst+1, acc[m].y);
        atomicAdd(dst+2, acc[m].z);
        atomicAdd(dst+3, acc[m].w);
      }
    }

    // hierarchical barrier, epoch e = t+1 (monotonic counters, no reset)
    __syncthreads();
    if (tid == 0) {
      unsigned e = (unsigned)(t + 1);
      unsigned np = __hip_atomic_fetch_add(arr, 1u, __ATOMIC_RELEASE, AGENT);
      if (np == e*32u - 1u) {                       // last arrival of this group
        unsigned gp = __hip_atomic_fetch_add(gcnt, 1u, __ATOMIC_RELEASE, AGENT);
        if (gp == e*8u - 1u) {                      // last group: broadcast release
          #pragma unroll
          for (int g2 = 0; g2 < 8; g2++)
            __hip_atomic_store(bar + 288 + g2*32, e, __ATOMIC_RELAXED, AGENT);
        }
      }
      while (__hip_atomic_load(rel, __ATOMIC_RELAXED, AGENT) < e)
        __builtin_amdgcn_s_sleep(1);
      __atomic_signal_fence(__ATOMIC_ACQUIRE);
    }
    __syncthreads();
  }
}

// ---------------- normalize alpha_b rows t=0..62 by invG (row 63 done in k_lastbel)
__global__ __launch_bounds__(128) void k_norm(float* __restrict__ alpha_b,
                                              const float* __restrict__ Gacc) {
  int row = blockIdx.x;                 // 4032 = 63 t * 64 n
  int t = row >> 6, n = row & 63;
  float inv = 1.f / Gacc[t*64 + n];
  float4* p = (float4*)(alpha_b + ((size_t)t*BB + n)*SS);
  float4 x = p[threadIdx.x];
  x.x *= inv; x.y *= inv; x.z *= inv; x.w *= inv;
  p[threadIdx.x] = x;
}

// ---------------- final belief (t=63) from X1 (apply invG(62))
__global__ __launch_bounds__(512) void k_lastbel(const float* __restrict__ X,
                                                 const float* __restrict__ lpo,
                                                 const float* __restrict__ Gacc,
                                                 float* __restrict__ alpha_b) {
  __shared__ float red[512];
  int n = blockIdx.x, j = threadIdx.x;
  float invG = 1.f / Gacc[62*64 + n];
  size_t off = (size_t)n*SS + j;
  float gv = fmaf(X[off], invG, EPS) * __expf(lpo[((size_t)63*BB + n)*SS + j]);
  red[j] = gv; __syncthreads();
  for (int s = 256; s > 0; s >>= 1) { if (j < s) red[j] += red[j+s]; __syncthreads(); }
  float inv = 1.f / red[0];
  alpha_b[((size_t)63*BB + n)*SS + j] = gv * inv;
}

// ---------------- plan(): 512 blocks (n x hk-eighth) x 256 thr, 8t x 2hk reg tile
__global__ __launch_bounds__(256) void k_pi(const float* __restrict__ alpha_b,
                                            const float* __restrict__ value,
                                            const float* __restrict__ pdf,
                                            float* __restrict__ alpha_pi) {
  __shared__ float Ab_l[64][132];   // i-tile of 128, pad 4
  __shared__ float lg[64][68];      // logits [t][hk_local 64]
  __shared__ float pdf_l[HH];
  int tid = threadIdx.x, bx = blockIdx.x;
  int n = bx >> 3, e = bx & 7;
  if (tid < HH) pdf_l[tid] = pdf[tid];
  int hkg = tid >> 3, tg = tid & 7;
  int hk0 = e*64 + hkg*2;
  const float* V0 = value + (((size_t)(hk0    >> 4)*BB + n)*AA + (hk0     & 15))*SS;
  const float* V1 = value + (((size_t)((hk0+1) >> 4)*BB + n)*AA + ((hk0+1) & 15))*SS;

  float4 a0[8], a1[8];
  #pragma unroll
  for (int m = 0; m < 8; m++) { a0[m] = make_float4(0,0,0,0); a1[m] = make_float4(0,0,0,0); }

  for (int it = 0; it < 4; it++) {
    __syncthreads();
    #pragma unroll
    for (int q = 0; q < 8; q++) {
      int idx = q*256 + tid;
      int tt = idx >> 5, il4 = (idx & 31)*4;
      float4 ab = *(const float4*)(alpha_b + ((size_t)tt*BB + n)*SS + it*128 + il4);
      *(float4*)&Ab_l[tt][il4] = ab;
    }
    __syncthreads();
    #pragma unroll 4
    for (int iq = 0; iq < 32; iq++) {
      float4 v0 = *(const float4*)(V0 + it*128 + iq*4);
      float4 v1 = *(const float4*)(V1 + it*128 + iq*4);
      #pragma unroll
      for (int tt = 0; tt < 8; tt++) {
        float4 ab = *(const float4*)&Ab_l[tt*8 + tg][iq*4];
        a0[tt].x = fmaf(ab.x, v0.x, a0[tt].x);
        a0[tt].y = fmaf(ab.y, v0.y, a0[tt].y);
        a0[tt].z = fmaf(ab.z, v0.z, a0[tt].z);
        a0[tt].w = fmaf(ab.w, v0.w, a0[tt].w);
        a1[tt].x = fmaf(ab.x, v1.x, a1[tt].x);
        a1[tt].y = fmaf(ab.y, v1.y, a1[tt].y);
        a1[tt].z = fmaf(ab.z, v1.z, a1[tt].z);
        a1[tt].w = fmaf(ab.w, v1.w, a1[tt].w);
      }
    }
  }
  #pragma unroll
  for (int tt = 0; tt < 8; tt++) {
    lg[tt*8 + tg][hkg*2 + 0] = a0[tt].x + a0[tt].y + a0[tt].z + a0[tt].w;
    lg[tt*8 + tg][hkg*2 + 1] = a1[tt].x + a1[tt].y + a1[tt].z + a1[tt].w;
  }
  __syncthreads();

  // softmax over k for (t, local h): 64t x 4h = 256 threads
  {
    int t = tid >> 2, hh = tid & 3;
    float* row = &lg[t][hh*16];
    float m = row[0];
    #pragma unroll
    for (int k2 = 1; k2 < 16; k2++) m = fmaxf(m, row[k2]);
    float ex[16]; float s = 0.f;
    #pragma unroll
    for (int k2 = 0; k2 < 16; k2++) { ex[k2] = __expf(row[k2]-m); s += ex[k2]; }
    float w = pdf_l[e*4 + hh] / s;
    #pragma unroll
    for (int k2 = 0; k2 < 16; k2++) row[k2] = ex[k2]*w;
  }
  __syncthreads();

  // combine 4 local h and atomic into alpha_pi
  #pragma unroll
  for (int q = 0; q < 4; q++) {
    int idx = q*256 + tid;           // 1024 = 64t x 16k
    int t = idx >> 4, k2 = idx & 15;
    float s = lg[t][0*16+k2] + lg[t][1*16+k2] + lg[t][2*16+k2] + lg[t][3*16+k2];
    atomicAdd(alpha_pi + ((size_t)t*BB + n)*AA + k2, s);
  }
}

extern "C" void kernel_launch(void* const* d_in, const int* in_sizes, int n_in,
                              void* d_out, int out_size, void* d_ws, size_t ws_size,
                              hipStream_t stream) {
  const float* lpo   = (const float*)d_in[0];
  const float* lpu   = (const float*)d_in[1];
  const float* value = (const float*)d_in[2];
  const float* b     = (const float*)d_in[3];
  const float* u     = (const float*)d_in[4];
  const float* v     = (const float*)d_in[5];
  const float* tau   = (const float*)d_in[6];
  float* out = (float*)d_out;
  float* ws  = (float*)d_ws;

  float* Tr  = ws + WS_TR;
  float* aT  = ws + WS_AT;
  float* pdf = ws + WS_PDF;
  float* X0  = ws + WS_X0;
  float* X1  = ws + WS_X1;
  float* X2  = ws + WS_X2;
  unsigned* bar = (unsigned*)(ws + WS_BAR);
  float* Gacc = ws + WS_G;

  float* alpha_b  = out;
  float* alpha_pi = out + (size_t)TT*BB*SS;

  hipLaunchKernelGGL(k_trans2,  dim3(512), dim3(256), 0, stream, u, v, Tr);
  hipLaunchKernelGGL(k_alpha_a, dim3(16),  dim3(256), 0, stream, lpu, aT);
  hipLaunchKernelGGL(k_taupdf,  dim3(1),   dim3(64),  0, stream, tau, pdf);
  hipLaunchKernelGGL(k_zero,    dim3(256), dim3(256), 0, stream, X1, X2, bar, alpha_pi, Gacc);

  void* args[10];
  args[0] = (void*)&Tr;  args[1] = (void*)&aT;  args[2] = (void*)&lpo;
  args[3] = (void*)&b;   args[4] = (void*)&X0;  args[5] = (void*)&X1;
  args[6] = (void*)&X2;  args[7] = (void*)&alpha_b; args[8] = (void*)&Gacc;
  args[9] = (void*)&bar;
  hipLaunchCooperativeKernel(k_scan, dim3(256), dim3(512), args, 0, stream);

  hipLaunchKernelGGL(k_norm,    dim3(4032), dim3(128), 0, stream, alpha_b, Gacc);
  hipLaunchKernelGGL(k_lastbel, dim3(64), dim3(512), 0, stream, X1, lpo, Gacc, alpha_b);
  hipLaunchKernelGGL(k_pi, dim3(512), dim3(256), 0, stream, alpha_b, value, pdf, alpha_pi);
}

// Round 12
// 1181.048 us; speedup vs baseline: 3.0519x; 1.0052x over previous
//
#include <hip/hip_runtime.h>
#include <cmath>

#define TT 64
#define BB 64
#define SS 512
#define AA 16
#define RR 64
#define HH 32
#define EPS 1e-6f

// ws layout in floats
#define WS_TR   0                         // transition [A][S][S] = 4194304
#define WS_AT   4194304                   // alpha_a transposed [T][A][B] = 65536
#define WS_PDF  (WS_AT + 65536)           // tau_pdf [32]
#define WS_X0   (WS_PDF + 32)             // sigma buf 0 [B][S] = 32768
#define WS_X1   (WS_X0 + 32768)           // sigma buf 1
#define WS_X2   (WS_X1 + 32768)           // sigma buf 2
#define WS_BAR  (WS_X2 + 32768)           // barrier region (1024 uints)
#define WS_G    (WS_BAR + 1024)           // Gacc [64 t][64 n] = 4096

#define AGENT __HIP_MEMORY_SCOPE_AGENT

__device__ __forceinline__ float aload(const float* p) {
  return __hip_atomic_load(p, __ATOMIC_RELAXED, AGENT);
}
__device__ __forceinline__ void astore(float* p, float v) {
  __hip_atomic_store(p, v, __ATOMIC_RELAXED, AGENT);
}

// ---------------- transition
__global__ __launch_bounds__(256) void k_trans2(const float* __restrict__ u,
                                                const float* __restrict__ v,
                                                float* __restrict__ Tr) {
  int bx = blockIdx.x;
  int k = bx >> 5, ic = bx & 31, i0 = ic * 16;
  __shared__ float urot_s[16][68];
  __shared__ float ut_s[64][68];
  __shared__ float w_s[16][516];
  int tid = threadIdx.x;
  int lane = tid & 63, wv = tid >> 6;

  float vkm = v[k*RR + lane];
  float n2 = vkm * vkm;
  #pragma unroll
  for (int o = 32; o > 0; o >>= 1) n2 += __shfl_xor(n2, o, 64);

  #pragma unroll
  for (int r = 0; r < 4; r++) {
    int il = wv*4 + r;
    float um = u[(size_t)(i0 + il)*RR + lane];
    float dt = um * vkm;
    #pragma unroll
    for (int o = 32; o > 0; o >>= 1) dt += __shfl_xor(dt, o, 64);
    urot_s[il][lane] = um - (2.f * dt / n2) * vkm;
  }

  int il = tid >> 4, jl4 = (tid & 15) * 4;
  for (int jt = 0; jt < 8; jt++) {
    __syncthreads();
    #pragma unroll
    for (int q = 0; q < 4; q++) {
      int fi = q*256 + tid;
      int r = fi >> 4, c4 = (fi & 15) * 4;
      float4 uu = *(const float4*)(u + (size_t)(jt*64 + r)*RR + c4);
      ut_s[c4+0][r] = uu.x; ut_s[c4+1][r] = uu.y;
      ut_s[c4+2][r] = uu.z; ut_s[c4+3][r] = uu.w;
    }
    __syncthreads();
    float4 acc = {0.f, 0.f, 0.f, 0.f};
    #pragma unroll 8
    for (int m = 0; m < 64; m++) {
      float ur = urot_s[il][m];
      float4 uu = *(const float4*)&ut_s[m][jl4];
      acc.x = fmaf(ur, uu.x, acc.x);
      acc.y = fmaf(ur, uu.y, acc.y);
      acc.z = fmaf(ur, uu.z, acc.z);
      acc.w = fmaf(ur, uu.w, acc.w);
    }
    *(float4*)&w_s[il][jt*64 + jl4] = acc;
  }
  __syncthreads();

  #pragma unroll
  for (int r = 0; r < 4; r++) {
    int ir = wv*4 + r;
    float vals[8]; float mx = -1e30f;
    #pragma unroll
    for (int q = 0; q < 8; q++) { vals[q] = w_s[ir][q*64 + lane]; mx = fmaxf(mx, vals[q]); }
    #pragma unroll
    for (int o = 32; o > 0; o >>= 1) mx = fmaxf(mx, __shfl_xor(mx, o, 64));
    float sm = 0.f;
    #pragma unroll
    for (int q = 0; q < 8; q++) { vals[q] = __expf(vals[q] - mx); sm += vals[q]; }
    #pragma unroll
    for (int o = 32; o > 0; o >>= 1) sm += __shfl_xor(sm, o, 64);
    float inv = 1.f / sm;
    #pragma unroll
    for (int q = 0; q < 8; q++)
      Tr[((size_t)k*SS + (i0 + ir))*SS + q*64 + lane] = vals[q] * inv;
  }
}

// ---------------- alpha_a transposed [T][A][B]
__global__ __launch_bounds__(256) void k_alpha_a(const float* __restrict__ lpu,
                                                 float* __restrict__ aT) {
  int idx = blockIdx.x*256 + threadIdx.x;
  int t = idx >> 6, n = idx & 63;
  const float* x = lpu + (size_t)idx * AA;
  float xs[AA]; float m = -1e30f;
  #pragma unroll
  for (int k = 0; k < AA; k++) { xs[k] = x[k]; m = fmaxf(m, xs[k]); }
  float s = 0.f;
  #pragma unroll
  for (int k = 0; k < AA; k++) { xs[k] = __expf(xs[k]-m); s += xs[k]; }
  float inv = 1.f/s;
  #pragma unroll
  for (int k = 0; k < AA; k++) aT[t*(AA*BB) + k*BB + n] = xs[k]*inv;
}

// ---------------- Poisson pdf
__global__ void k_taupdf(const float* __restrict__ tau, float* __restrict__ pdf) {
  __shared__ float pl[HH]; __shared__ float ss;
  int tid = threadIdx.x;
  float rate = log1pf(expf(tau[0]));
  if (tid < HH) {
    float kk = (float)(tid+1);
    pl[tid] = expf(kk*logf(rate) - rate - lgammaf(kk+1.f));
  }
  __syncthreads();
  if (tid == 0) { float s = 0.f; for (int h = 0; h < HH; h++) s += pl[h]; ss = 1.f/s; }
  __syncthreads();
  if (tid < HH) pdf[tid] = pl[tid]*ss;
}

// ---------------- zero X1/X2, barrier region, Gacc, alpha_pi
__global__ __launch_bounds__(256) void k_zero(float* __restrict__ X1,
                                              float* __restrict__ X2,
                                              unsigned* __restrict__ bar,
                                              float* __restrict__ alpha_pi,
                                              float* __restrict__ Gacc) {
  int idx = blockIdx.x*256 + threadIdx.x;   // grid 256*256 = 65536
  if (idx < 32768) { X1[idx] = 0.f; X2[idx] = 0.f; }
  if (idx < 1024) bar[idx] = 0u;
  if (idx < 4096) Gacc[idx] = 0.f;
  alpha_pi[idx] = 0.f;                      // 65536 floats
}

// ---------------- persistent scan: 256 blocks x 512 thr, hierarchical barrier
// r11 structure (verified 1046 us) with sync #1 DELETED: invG is now a
// wave-local shuffle broadcast (lanes 0-7 load the wave's 8 needed Gacc
// values; __shfl distributes) instead of an LDS array + block barrier.
// Arithmetic identical (same 1/x, same consumption). Prior-step bel_s/a_s
// read-vs-write hazards remain sealed by the grid barrier's closing
// __syncthreads. Xz zeroing spread across all 256 blocks (was blocks 0-63).
// Normalization carried one step behind via scalar G[n]; alpha_b written
// unnormalized (k_norm fixes rows 0..62, k_lastbel row 63).
__global__ __launch_bounds__(512) void k_scan(const float* __restrict__ Tr,
                                              const float* __restrict__ aT,
                                              const float* __restrict__ lpo,
                                              const float* __restrict__ b,
                                              float* __restrict__ X0,
                                              float* __restrict__ X1,
                                              float* __restrict__ X2,
                                              float* __restrict__ alpha_b,
                                              float* __restrict__ Gacc,
                                              unsigned* __restrict__ bar) {
  __shared__ float TrL[16*32*32];  // 64 KB staged transition slice [k][i_local][j_local]
  __shared__ float bel_s[32*68];   // stride 68: 8 ii-rows hit 8 distinct bank groups
  __shared__ float a_s[16*64];
  int tid = threadIdx.x, bx = blockIdx.x;
  int jc = bx & 15, ic = bx >> 4;
  int i0 = ic*32, j0 = jc*32;
  int g = bx & 7;
  unsigned* arr = bar + g*32;
  unsigned* gcnt = bar + 256;
  unsigned* rel = bar + 288 + g*32;
  int lane = tid & 63, wv = tid >> 6;      // wave id 0..7
  int r5 = (tid >> 5) & 1;                 // low/high half of wave

  // one-time stage of Tr slice: 4096 float4, contiguous b128 writes (conflict-free)
  #pragma unroll
  for (int q = 0; q < 8; q++) {
    int f = q*512 + tid;
    int k = f >> 8, rem = f & 255;
    int i = rem >> 3, j4 = rem & 7;
    float4 tv = *(const float4*)(Tr + ((size_t)k*SS + i0 + i)*SS + j0 + j4*4);
    *(float4*)&TrL[(k*32 + i)*32 + j4*4] = tv;
  }
  __syncthreads();

  float lp_pf[4];                  // prefetched lpo[t] (consumed at t+1)

  for (int t = 0; t < TT; t++) {
    const float* Xr; float* Xw; float* Xz;
    {
      int r = t % 3;
      if (r == 0)      { Xr = X0; Xw = X1; Xz = X2; }
      else if (r == 1) { Xr = X1; Xw = X2; Xz = X0; }
      else             { Xr = X2; Xw = X0; Xz = X1; }
    }

    // zero next-next buffer, spread over all blocks (128 floats each)
    if (tid < 128) astore(Xz + bx*128 + tid, 0.f);

    // invG via wave-local shuffle: lanes 0-7 load this wave's 8 Gacc values
    // (nn = (lane>>1)*16 + 2*wv + (lane&1)), precise reciprocal, shfl out.
    // No LDS, no block barrier. For t<2 invG = 1.0 exactly.
    float invg_src = 1.f;
    if (t >= 2 && lane < 8)
      invg_src = aload(Gacc + (size_t)(t-2)*64 + (lane>>1)*16 + 2*wv + (lane&1));
    invg_src = (lane < 8) ? 1.f / invg_src : 0.f;

    // bel pass: bel_s slice (unnormalized g), lpo from prefetch regs
    if (t == 0) {
      #pragma unroll
      for (int q = 0; q < 4; q++) {
        int idx = q*512 + tid;
        int nn = idx >> 5, il = idx & 31;
        bel_s[il*68 + nn] = b[(size_t)nn*SS + i0 + il];
      }
    } else {
      #pragma unroll
      for (int q = 0; q < 4; q++) {
        int idx = q*512 + tid;
        int nn = idx >> 5, il = idx & 31;
        size_t off = (size_t)nn*SS + i0 + il;
        float ivg = __shfl(invg_src, q*2 + r5, 64);
        float val = fmaf(aload(Xr + off), ivg, EPS) * __expf(lp_pf[q]);
        bel_s[il*68 + nn] = val;
        if (ic == jc) astore(alpha_b + ((size_t)(t-1)*BB + nn)*SS + i0 + il, val);
      }
    }
    if (tid < 256) *(float4*)&a_s[tid*4] = *(const float4*)(aT + (size_t)t*1024 + tid*4);
    __syncthreads();

    // prefetch lpo[t] for next step's bel pass (in flight during GEMM)
    #pragma unroll
    for (int q = 0; q < 4; q++) {
      int idx = q*512 + tid;
      int nn = idx >> 5, il = idx & 31;
      lp_pf[q] = lpo[(size_t)t*BB*SS + (size_t)nn*SS + i0 + il];
    }

    // diagonal blocks: partial G(t-1) over this i-slice (consumed at t+1)
    if (t >= 1 && ic == jc && tid < 64) {
      float s = 0.f;
      #pragma unroll
      for (int il2 = 0; il2 < 32; il2++) s += bel_s[il2*68 + tid];
      atomicAdd(Gacc + (size_t)(t-1)*64 + tid, s);
    }

    // GEMM (all operands in LDS)
    int jq = tid & 7, ii = (tid >> 3) & 7, nq = tid >> 6;
    int n0 = nq*8;
    float4 acc[8];
    #pragma unroll
    for (int m = 0; m < 8; m++) acc[m] = make_float4(0.f, 0.f, 0.f, 0.f);
    const float* TrBase = TrL + ii*32 + jq*4;

    // bf is kb-invariant: load once (8 b128 instead of 32)
    float bf[4][8];
    #pragma unroll
    for (int io = 0; io < 4; io++) {
      *(float4*)&bf[io][0] = *(float4*)&bel_s[(io*8+ii)*68 + n0];
      *(float4*)&bf[io][4] = *(float4*)&bel_s[(io*8+ii)*68 + n0 + 4];
    }

    for (int kb = 0; kb < 4; kb++) {
      float af[4][8];
      #pragma unroll
      for (int kk = 0; kk < 4; kk++) {
        *(float4*)&af[kk][0] = *(float4*)&a_s[(kb*4+kk)*64 + n0];
        *(float4*)&af[kk][4] = *(float4*)&a_s[(kb*4+kk)*64 + n0 + 4];
      }
      #pragma unroll
      for (int io = 0; io < 4; io++) {
        #pragma unroll
        for (int kk = 0; kk < 4; kk++) {
          float4 tv = *(const float4*)(TrBase + (kb*4+kk)*1024 + io*256);
          #pragma unroll
          for (int m = 0; m < 8; m++) {
            float w = af[kk][m] * bf[io][m];
            acc[m].x = fmaf(w, tv.x, acc[m].x);
            acc[m].y = fmaf(w, tv.y, acc[m].y);
            acc[m].z = fmaf(w, tv.z, acc[m].z);
            acc[m].w = fmaf(w, tv.w, acc[m].w);
          }
        }
      }
    }

    #pragma unroll
    for (int m = 0; m < 8; m++) {
      #pragma unroll
      for (int o = 8; o <= 32; o <<= 1) {
        acc[m].x += __shfl_xor(acc[m].x, o, 64);
        acc[m].y += __shfl_xor(acc[m].y, o, 64);
        acc[m].z += __shfl_xor(acc[m].z, o, 64);
        acc[m].w += __shfl_xor(acc[m].w, o, 64);
      }
    }
    if (ii == 0) {
      #pragma unroll
      for (int m = 0; m < 8; m++) {
        float* dst = Xw + (size_t)(n0+m)*SS + j0 + jq*4;
        atomicAdd(dst+0, acc[m].x);
        atomicAdd(dst+1, acc[m].y);
        atomicAdd(dst+2, acc[m].z);
        atomicAdd(dst+3, acc[m].w);
      }
    }

    // hierarchical barrier, epoch e = t+1 (monotonic counters, no reset)
    __syncthreads();
    if (tid == 0) {
      unsigned e = (unsigned)(t + 1);
      unsigned np = __hip_atomic_fetch_add(arr, 1u, __ATOMIC_RELEASE, AGENT);
      if (np == e*32u - 1u) {                       // last arrival of this group
        unsigned gp = __hip_atomic_fetch_add(gcnt, 1u, __ATOMIC_RELEASE, AGENT);
        if (gp == e*8u - 1u) {                      // last group: broadcast release
          #pragma unroll
          for (int g2 = 0; g2 < 8; g2++)
            __hip_atomic_store(bar + 288 + g2*32, e, __ATOMIC_RELAXED, AGENT);
        }
      }
      while (__hip_atomic_load(rel, __ATOMIC_RELAXED, AGENT) < e)
        __builtin_amdgcn_s_sleep(1);
      __atomic_signal_fence(__ATOMIC_ACQUIRE);
    }
    __syncthreads();
  }
}

// ---------------- normalize alpha_b rows t=0..62 by invG (row 63 done in k_lastbel)
__global__ __launch_bounds__(128) void k_norm(float* __restrict__ alpha_b,
                                              const float* __restrict__ Gacc) {
  int row = blockIdx.x;                 // 4032 = 63 t * 64 n
  int t = row >> 6, n = row & 63;
  float inv = 1.f / Gacc[t*64 + n];
  float4* p = (float4*)(alpha_b + ((size_t)t*BB + n)*SS);
  float4 x = p[threadIdx.x];
  x.x *= inv; x.y *= inv; x.z *= inv; x.w *= inv;
  p[threadIdx.x] = x;
}

// ---------------- final belief (t=63) from X1 (apply invG(62))
__global__ __launch_bounds__(512) void k_lastbel(const float* __restrict__ X,
                                                 const float* __restrict__ lpo,
                                                 const float* __restrict__ Gacc,
                                                 float* __restrict__ alpha_b) {
  __shared__ float red[512];
  int n = blockIdx.x, j = threadIdx.x;
  float invG = 1.f / Gacc[62*64 + n];
  size_t off = (size_t)n*SS + j;
  float gv = fmaf(X[off], invG, EPS) * __expf(lpo[((size_t)63*BB + n)*SS + j]);
  red[j] = gv; __syncthreads();
  for (int s = 256; s > 0; s >>= 1) { if (j < s) red[j] += red[j+s]; __syncthreads(); }
  float inv = 1.f / red[0];
  alpha_b[((size_t)63*BB + n)*SS + j] = gv * inv;
}

// ---------------- plan(): 512 blocks (n x hk-eighth) x 256 thr, 8t x 2hk reg tile
__global__ __launch_bounds__(256) void k_pi(const float* __restrict__ alpha_b,
                                            const float* __restrict__ value,
                                            const float* __restrict__ pdf,
                                            float* __restrict__ alpha_pi) {
  __shared__ float Ab_l[64][132];   // i-tile of 128, pad 4
  __shared__ float lg[64][68];      // logits [t][hk_local 64]
  __shared__ float pdf_l[HH];
  int tid = threadIdx.x, bx = blockIdx.x;
  int n = bx >> 3, e = bx & 7;
  if (tid < HH) pdf_l[tid] = pdf[tid];
  int hkg = tid >> 3, tg = tid & 7;
  int hk0 = e*64 + hkg*2;
  const float* V0 = value + (((size_t)(hk0    >> 4)*BB + n)*AA + (hk0     & 15))*SS;
  const float* V1 = value + (((size_t)((hk0+1) >> 4)*BB + n)*AA + ((hk0+1) & 15))*SS;

  float4 a0[8], a1[8];
  #pragma unroll
  for (int m = 0; m < 8; m++) { a0[m] = make_float4(0,0,0,0); a1[m] = make_float4(0,0,0,0); }

  for (int it = 0; it < 4; it++) {
    __syncthreads();
    #pragma unroll
    for (int q = 0; q < 8; q++) {
      int idx = q*256 + tid;
      int tt = idx >> 5, il4 = (idx & 31)*4;
      float4 ab = *(const float4*)(alpha_b + ((size_t)tt*BB + n)*SS + it*128 + il4);
      *(float4*)&Ab_l[tt][il4] = ab;
    }
    __syncthreads();
    #pragma unroll 4
    for (int iq = 0; iq < 32; iq++) {
      float4 v0 = *(const float4*)(V0 + it*128 + iq*4);
      float4 v1 = *(const float4*)(V1 + it*128 + iq*4);
      #pragma unroll
      for (int tt = 0; tt < 8; tt++) {
        float4 ab = *(const float4*)&Ab_l[tt*8 + tg][iq*4];
        a0[tt].x = fmaf(ab.x, v0.x, a0[tt].x);
        a0[tt].y = fmaf(ab.y, v0.y, a0[tt].y);
        a0[tt].z = fmaf(ab.z, v0.z, a0[tt].z);
        a0[tt].w = fmaf(ab.w, v0.w, a0[tt].w);
        a1[tt].x = fmaf(ab.x, v1.x, a1[tt].x);
        a1[tt].y = fmaf(ab.y, v1.y, a1[tt].y);
        a1[tt].z = fmaf(ab.z, v1.z, a1[tt].z);
        a1[tt].w = fmaf(ab.w, v1.w, a1[tt].w);
      }
    }
  }
  #pragma unroll
  for (int tt = 0; tt < 8; tt++) {
    lg[tt*8 + tg][hkg*2 + 0] = a0[tt].x + a0[tt].y + a0[tt].z + a0[tt].w;
    lg[tt*8 + tg][hkg*2 + 1] = a1[tt].x + a1[tt].y + a1[tt].z + a1[tt].w;
  }
  __syncthreads();

  // softmax over k for (t, local h): 64t x 4h = 256 threads
  {
    int t = tid >> 2, hh = tid & 3;
    float* row = &lg[t][hh*16];
    float m = row[0];
    #pragma unroll
    for (int k2 = 1; k2 < 16; k2++) m = fmaxf(m, row[k2]);
    float ex[16]; float s = 0.f;
    #pragma unroll
    for (int k2 = 0; k2 < 16; k2++) { ex[k2] = __expf(row[k2]-m); s += ex[k2]; }
    float w = pdf_l[e*4 + hh] / s;
    #pragma unroll
    for (int k2 = 0; k2 < 16; k2++) row[k2] = ex[k2]*w;
  }
  __syncthreads();

  // combine 4 local h and atomic into alpha_pi
  #pragma unroll
  for (int q = 0; q < 4; q++) {
    int idx = q*256 + tid;           // 1024 = 64t x 16k
    int t = idx >> 4, k2 = idx & 15;
    float s = lg[t][0*16+k2] + lg[t][1*16+k2] + lg[t][2*16+k2] + lg[t][3*16+k2];
    atomicAdd(alpha_pi + ((size_t)t*BB + n)*AA + k2, s);
  }
}

extern "C" void kernel_launch(void* const* d_in, const int* in_sizes, int n_in,
                              void* d_out, int out_size, void* d_ws, size_t ws_size,
                              hipStream_t stream) {
  const float* lpo   = (const float*)d_in[0];
  const float* lpu   = (const float*)d_in[1];
  const float* value = (const float*)d_in[2];
  const float* b     = (const float*)d_in[3];
  const float* u     = (const float*)d_in[4];
  const float* v     = (const float*)d_in[5];
  const float* tau   = (const float*)d_in[6];
  float* out = (float*)d_out;
  float* ws  = (float*)d_ws;

  float* Tr  = ws + WS_TR;
  float* aT  = ws + WS_AT;
  float* pdf = ws + WS_PDF;
  float* X0  = ws + WS_X0;
  float* X1  = ws + WS_X1;
  float* X2  = ws + WS_X2;
  unsigned* bar = (unsigned*)(ws + WS_BAR);
  float* Gacc = ws + WS_G;

  float* alpha_b  = out;
  float* alpha_pi = out + (size_t)TT*BB*SS;

  hipLaunchKernelGGL(k_trans2,  dim3(512), dim3(256), 0, stream, u, v, Tr);
  hipLaunchKernelGGL(k_alpha_a, dim3(16),  dim3(256), 0, stream, lpu, aT);
  hipLaunchKernelGGL(k_taupdf,  dim3(1),   dim3(64),  0, stream, tau, pdf);
  hipLaunchKernelGGL(k_zero,    dim3(256), dim3(256), 0, stream, X1, X2, bar, alpha_pi, Gacc);

  void* args[10];
  args[0] = (void*)&Tr;  args[1] = (void*)&aT;  args[2] = (void*)&lpo;
  args[3] = (void*)&b;   args[4] = (void*)&X0;  args[5] = (void*)&X1;
  args[6] = (void*)&X2;  args[7] = (void*)&alpha_b; args[8] = (void*)&Gacc;
  args[9] = (void*)&bar;
  hipLaunchCooperativeKernel(k_scan, dim3(256), dim3(512), args, 0, stream);

  hipLaunchKernelGGL(k_norm,    dim3(4032), dim3(128), 0, stream, alpha_b, Gacc);
  hipLaunchKernelGGL(k_lastbel, dim3(64), dim3(512), 0, stream, X1, lpo, Gacc, alpha_b);
  hipLaunchKernelGGL(k_pi, dim3(512), dim3(256), 0, stream, alpha_b, value, pdf, alpha_pi);
}

// Round 14
// 662.351 us; speedup vs baseline: 5.4419x; 1.7831x over previous
//
#include <hip/hip_runtime.h>
#include <cmath>

#define TT 64
#define BB 64
#define SS 512
#define AA 16
#define RR 64
#define HH 32
#define EPS 1e-6f

// ws layout in floats
#define WS_TR   0                         // transition [A][S][S] = 4194304
#define WS_AT   4194304                   // alpha_a transposed [T][A][B] = 65536
#define WS_PDF  (WS_AT + 65536)           // tau_pdf [32]
#define WS_X0   (WS_PDF + 32)             // sigma buf 0 [B][S] = 32768
#define WS_X1   (WS_X0 + 32768)           // sigma buf 1
#define WS_X2   (WS_X1 + 32768)           // sigma buf 2
#define WS_BAR  (WS_X2 + 32768)           // barrier region (1024 uints)
#define WS_G    (WS_BAR + 1024)           // Gacc [64 t][64 n] = 4096

#define AGENT __HIP_MEMORY_SCOPE_AGENT

__device__ __forceinline__ float aload(const float* p) {
  return __hip_atomic_load(p, __ATOMIC_RELAXED, AGENT);
}
__device__ __forceinline__ void astore(float* p, float v) {
  __hip_atomic_store(p, v, __ATOMIC_RELAXED, AGENT);
}

typedef short bf16x8 __attribute__((ext_vector_type(8)));
typedef float f32x4 __attribute__((ext_vector_type(4)));
union FragU { uint4 q; unsigned u[4]; bf16x8 v; };

__device__ __forceinline__ unsigned cvtpk_bf16(float a, float b) {
  unsigned r;
  asm("v_cvt_pk_bf16_f32 %0, %1, %2" : "=v"(r) : "v"(a), "v"(b));
  return r;
}

// ---------------- transition
__global__ __launch_bounds__(256) void k_trans2(const float* __restrict__ u,
                                                const float* __restrict__ v,
                                                float* __restrict__ Tr) {
  int bx = blockIdx.x;
  int k = bx >> 5, ic = bx & 31, i0 = ic * 16;
  __shared__ float urot_s[16][68];
  __shared__ float ut_s[64][68];
  __shared__ float w_s[16][516];
  int tid = threadIdx.x;
  int lane = tid & 63, wv = tid >> 6;

  float vkm = v[k*RR + lane];
  float n2 = vkm * vkm;
  #pragma unroll
  for (int o = 32; o > 0; o >>= 1) n2 += __shfl_xor(n2, o, 64);

  #pragma unroll
  for (int r = 0; r < 4; r++) {
    int il = wv*4 + r;
    float um = u[(size_t)(i0 + il)*RR + lane];
    float dt = um * vkm;
    #pragma unroll
    for (int o = 32; o > 0; o >>= 1) dt += __shfl_xor(dt, o, 64);
    urot_s[il][lane] = um - (2.f * dt / n2) * vkm;
  }

  int il = tid >> 4, jl4 = (tid & 15) * 4;
  for (int jt = 0; jt < 8; jt++) {
    __syncthreads();
    #pragma unroll
    for (int q = 0; q < 4; q++) {
      int fi = q*256 + tid;
      int r = fi >> 4, c4 = (fi & 15) * 4;
      float4 uu = *(const float4*)(u + (size_t)(jt*64 + r)*RR + c4);
      ut_s[c4+0][r] = uu.x; ut_s[c4+1][r] = uu.y;
      ut_s[c4+2][r] = uu.z; ut_s[c4+3][r] = uu.w;
    }
    __syncthreads();
    float4 acc = {0.f, 0.f, 0.f, 0.f};
    #pragma unroll 8
    for (int m = 0; m < 64; m++) {
      float ur = urot_s[il][m];
      float4 uu = *(const float4*)&ut_s[m][jl4];
      acc.x = fmaf(ur, uu.x, acc.x);
      acc.y = fmaf(ur, uu.y, acc.y);
      acc.z = fmaf(ur, uu.z, acc.z);
      acc.w = fmaf(ur, uu.w, acc.w);
    }
    *(float4*)&w_s[il][jt*64 + jl4] = acc;
  }
  __syncthreads();

  #pragma unroll
  for (int r = 0; r < 4; r++) {
    int ir = wv*4 + r;
    float vals[8]; float mx = -1e30f;
    #pragma unroll
    for (int q = 0; q < 8; q++) { vals[q] = w_s[ir][q*64 + lane]; mx = fmaxf(mx, vals[q]); }
    #pragma unroll
    for (int o = 32; o > 0; o >>= 1) mx = fmaxf(mx, __shfl_xor(mx, o, 64));
    float sm = 0.f;
    #pragma unroll
    for (int q = 0; q < 8; q++) { vals[q] = __expf(vals[q] - mx); sm += vals[q]; }
    #pragma unroll
    for (int o = 32; o > 0; o >>= 1) sm += __shfl_xor(sm, o, 64);
    float inv = 1.f / sm;
    #pragma unroll
    for (int q = 0; q < 8; q++)
      Tr[((size_t)k*SS + (i0 + ir))*SS + q*64 + lane] = vals[q] * inv;
  }
}

// ---------------- alpha_a transposed [T][A][B]
__global__ __launch_bounds__(256) void k_alpha_a(const float* __restrict__ lpu,
                                                 float* __restrict__ aT) {
  int idx = blockIdx.x*256 + threadIdx.x;
  int t = idx >> 6, n = idx & 63;
  const float* x = lpu + (size_t)idx * AA;
  float xs[AA]; float m = -1e30f;
  #pragma unroll
  for (int k = 0; k < AA; k++) { xs[k] = x[k]; m = fmaxf(m, xs[k]); }
  float s = 0.f;
  #pragma unroll
  for (int k = 0; k < AA; k++) { xs[k] = __expf(xs[k]-m); s += xs[k]; }
  float inv = 1.f/s;
  #pragma unroll
  for (int k = 0; k < AA; k++) aT[t*(AA*BB) + k*BB + n] = xs[k]*inv;
}

// ---------------- Poisson pdf
__global__ void k_taupdf(const float* __restrict__ tau, float* __restrict__ pdf) {
  __shared__ float pl[HH]; __shared__ float ss;
  int tid = threadIdx.x;
  float rate = log1pf(expf(tau[0]));
  if (tid < HH) {
    float kk = (float)(tid+1);
    pl[tid] = expf(kk*logf(rate) - rate - lgammaf(kk+1.f));
  }
  __syncthreads();
  if (tid == 0) { float s = 0.f; for (int h = 0; h < HH; h++) s += pl[h]; ss = 1.f/s; }
  __syncthreads();
  if (tid < HH) pdf[tid] = pl[tid]*ss;
}

// ---------------- zero X1/X2, barrier region, Gacc, alpha_pi
__global__ __launch_bounds__(256) void k_zero(float* __restrict__ X1,
                                              float* __restrict__ X2,
                                              unsigned* __restrict__ bar,
                                              float* __restrict__ alpha_pi,
                                              float* __restrict__ Gacc) {
  int idx = blockIdx.x*256 + threadIdx.x;   // grid 256*256 = 65536
  if (idx < 32768) { X1[idx] = 0.f; X2[idx] = 0.f; }
  if (idx < 1024) bar[idx] = 0u;
  if (idx < 4096) Gacc[idx] = 0.f;
  alpha_pi[idx] = 0.f;                      // 65536 floats
}

// ---------------- persistent scan: 256 blocks x 512 thr, hierarchical barrier
// r12 structure with the GEMM moved to MFMA (split-bf16, a kept fp32):
//   out[n][j] = sum_s a[s][n] * (sum_i bel[n][i]*Tr[s][i][j])
// Per wave (ntile 4 x jtile 2): per K-step s, one 16x16x32 bf16 MFMA triple
// (belhi*Trhi + belhi*Trlo + bello*Trhi) into tmp, then 4 FMA scale-add by
// a_s[s][row]. Tr fragments (hi/lo bf16) are TIME-INVARIANT: built once in
// the prologue, pre-swizzled in LDS (64 KB, replaces the old f32 TrL).
// Layout per m89-verified mapping: A-row/B-col = lane&15; D col=lane&15,
// row=(lane>>4)*4+reg. A/B share one packing convention (cvt_pk) so any
// K-ordering is self-consistent. Shuffle reduction deleted (K inside MFMA).
// invG via wave shuffle (r12); normalization one step behind via G[n].
__global__ __launch_bounds__(512) void k_scan(const float* __restrict__ Tr,
                                              const float* __restrict__ aT,
                                              const float* __restrict__ lpo,
                                              const float* __restrict__ b,
                                              float* __restrict__ X0,
                                              float* __restrict__ X1,
                                              float* __restrict__ X2,
                                              float* __restrict__ alpha_b,
                                              float* __restrict__ Gacc,
                                              unsigned* __restrict__ bar) {
  __shared__ unsigned TrF[16384];  // 64 KB: 32 sj x {hi,lo} x 64 lane x 4 u32
  __shared__ float bel_s[64*36];   // [n][i] stride 36 (16B-aligned rows)
  __shared__ float a_s[16*64];
  int tid = threadIdx.x, bx = blockIdx.x;
  int jc = bx & 15, ic = bx >> 4;
  int i0 = ic*32, j0 = jc*32;
  int g = bx & 7;
  unsigned* arr = bar + g*32;
  unsigned* gcnt = bar + 256;
  unsigned* rel = bar + 288 + g*32;
  int lane = tid & 63, wv = tid >> 6;      // wave id 0..7
  int r5 = (tid >> 5) & 1;                 // low/high half of wave
  int ntile = wv >> 1, j2w = wv & 1;       // GEMM tile mapping
  int mrow = lane & 15, kg = lane >> 4;

  // one-time build of pre-swizzled bf16 hi/lo Tr fragments (2048 slots, 4/thread)
  #pragma unroll
  for (int q = 0; q < 4; q++) {
    int slot = q*512 + tid;
    int sl = slot & 63;                 // fragment lane
    int sj = slot >> 6;                 // s*2 + jtile, 0..31
    int s = sj >> 1, j2 = sj & 1;
    int kr0 = (sl >> 4) * 8;
    int col = sl & 15;
    const float* src = Tr + ((size_t)s*SS + i0 + kr0)*SS + j0 + j2*16 + col;
    float f[8];
    #pragma unroll
    for (int e = 0; e < 8; e++) f[e] = src[(size_t)e*SS];
    unsigned hi[4], lo[4];
    #pragma unroll
    for (int r = 0; r < 4; r++) {
      hi[r] = cvtpk_bf16(f[2*r], f[2*r+1]);
      float g0 = f[2*r]   - __uint_as_float(hi[r] << 16);
      float g1 = f[2*r+1] - __uint_as_float(hi[r] & 0xFFFF0000u);
      lo[r] = cvtpk_bf16(g0, g1);
    }
    *(uint4*)&TrF[(sj*2+0)*256 + sl*4] = make_uint4(hi[0], hi[1], hi[2], hi[3]);
    *(uint4*)&TrF[(sj*2+1)*256 + sl*4] = make_uint4(lo[0], lo[1], lo[2], lo[3]);
  }
  __syncthreads();

  float lp_pf[4];                  // prefetched lpo[t] (consumed at t+1)

  for (int t = 0; t < TT; t++) {
    const float* Xr; float* Xw; float* Xz;
    {
      int r = t % 3;
      if (r == 0)      { Xr = X0; Xw = X1; Xz = X2; }
      else if (r == 1) { Xr = X1; Xw = X2; Xz = X0; }
      else             { Xr = X2; Xw = X0; Xz = X1; }
    }

    // zero next-next buffer, spread over all blocks (128 floats each)
    if (tid < 128) astore(Xz + bx*128 + tid, 0.f);

    // invG via wave-local shuffle (r12): lanes 0-7 load the wave's 8 Gacc values
    float invg_src = 1.f;
    if (t >= 2 && lane < 8)
      invg_src = aload(Gacc + (size_t)(t-2)*64 + (lane>>1)*16 + 2*wv + (lane&1));
    invg_src = (lane < 8) ? 1.f / invg_src : 0.f;

    // bel pass: bel_s [n][i] (unnormalized g), lpo from prefetch regs
    if (t == 0) {
      #pragma unroll
      for (int q = 0; q < 4; q++) {
        int idx = q*512 + tid;
        int nn = idx >> 5, il = idx & 31;
        bel_s[nn*36 + il] = b[(size_t)nn*SS + i0 + il];
      }
    } else {
      #pragma unroll
      for (int q = 0; q < 4; q++) {
        int idx = q*512 + tid;
        int nn = idx >> 5, il = idx & 31;
        size_t off = (size_t)nn*SS + i0 + il;
        float ivg = __shfl(invg_src, q*2 + r5, 64);
        float val = fmaf(aload(Xr + off), ivg, EPS) * __expf(lp_pf[q]);
        bel_s[nn*36 + il] = val;
        if (ic == jc) astore(alpha_b + ((size_t)(t-1)*BB + nn)*SS + i0 + il, val);
      }
    }
    if (tid < 256) *(float4*)&a_s[tid*4] = *(const float4*)(aT + (size_t)t*1024 + tid*4);
    __syncthreads();

    // prefetch lpo[t] for next step's bel pass (in flight during GEMM)
    #pragma unroll
    for (int q = 0; q < 4; q++) {
      int idx = q*512 + tid;
      int nn = idx >> 5, il = idx & 31;
      lp_pf[q] = lpo[(size_t)t*BB*SS + (size_t)nn*SS + i0 + il];
    }

    // diagonal blocks: partial G(t-1) over this i-slice (consumed at t+1)
    if (t >= 1 && ic == jc && tid < 64) {
      float s = 0.f;
      #pragma unroll
      for (int il2 = 0; il2 < 32; il2++) s += bel_s[tid*36 + il2];
      atomicAdd(Gacc + (size_t)(t-1)*64 + tid, s);
    }

    // ---- MFMA GEMM: wave (ntile, j2w) computes out[16n x 16j] tile
    // bel A-fragments (hi/lo), built once per step
    FragU Bh, Bl;
    {
      const float* bp = &bel_s[(ntile*16 + mrow)*36 + kg*8];
      float4 c0 = *(const float4*)bp;
      float4 c1 = *(const float4*)(bp + 4);
      float f[8] = {c0.x, c0.y, c0.z, c0.w, c1.x, c1.y, c1.z, c1.w};
      #pragma unroll
      for (int r = 0; r < 4; r++) {
        Bh.u[r] = cvtpk_bf16(f[2*r], f[2*r+1]);
        float g0 = f[2*r]   - __uint_as_float(Bh.u[r] << 16);
        float g1 = f[2*r+1] - __uint_as_float(Bh.u[r] & 0xFFFF0000u);
        Bl.u[r] = cvtpk_bf16(g0, g1);
      }
    }
    f32x4 acc = {0.f, 0.f, 0.f, 0.f};
    #pragma unroll 4
    for (int s = 0; s < 16; s++) {
      int sj = s*2 + j2w;
      FragU Th, Tl;
      Th.q = *(const uint4*)&TrF[(sj*2+0)*256 + lane*4];
      Tl.q = *(const uint4*)&TrF[(sj*2+1)*256 + lane*4];
      f32x4 tmp = {0.f, 0.f, 0.f, 0.f};
      tmp = __builtin_amdgcn_mfma_f32_16x16x32_bf16(Bh.v, Th.v, tmp, 0, 0, 0);
      tmp = __builtin_amdgcn_mfma_f32_16x16x32_bf16(Bh.v, Tl.v, tmp, 0, 0, 0);
      tmp = __builtin_amdgcn_mfma_f32_16x16x32_bf16(Bl.v, Th.v, tmp, 0, 0, 0);
      float4 av = *(const float4*)&a_s[s*64 + ntile*16 + kg*4];
      acc[0] = fmaf(av.x, tmp[0], acc[0]);
      acc[1] = fmaf(av.y, tmp[1], acc[1]);
      acc[2] = fmaf(av.z, tmp[2], acc[2]);
      acc[3] = fmaf(av.w, tmp[3], acc[3]);
    }
    // D: row = ntile*16 + kg*4 + r (n), col = j0 + j2w*16 + mrow (j)
    {
      float* dst = Xw + (size_t)(ntile*16 + kg*4)*SS + j0 + j2w*16 + mrow;
      atomicAdd(dst,          acc[0]);
      atomicAdd(dst + SS,     acc[1]);
      atomicAdd(dst + 2*SS,   acc[2]);
      atomicAdd(dst + 3*SS,   acc[3]);
    }

    // hierarchical barrier, epoch e = t+1 (monotonic counters, no reset)
    __syncthreads();
    if (tid == 0) {
      unsigned e = (unsigned)(t + 1);
      unsigned np = __hip_atomic_fetch_add(arr, 1u, __ATOMIC_RELEASE, AGENT);
      if (np == e*32u - 1u) {                       // last arrival of this group
        unsigned gp = __hip_atomic_fetch_add(gcnt, 1u, __ATOMIC_RELEASE, AGENT);
        if (gp == e*8u - 1u) {                      // last group: broadcast release
          #pragma unroll
          for (int g2 = 0; g2 < 8; g2++)
            __hip_atomic_store(bar + 288 + g2*32, e, __ATOMIC_RELAXED, AGENT);
        }
      }
      while (__hip_atomic_load(rel, __ATOMIC_RELAXED, AGENT) < e)
        __builtin_amdgcn_s_sleep(1);
      __atomic_signal_fence(__ATOMIC_ACQUIRE);
    }
    __syncthreads();
  }
}

// ---------------- normalize alpha_b rows t=0..62 by invG (row 63 done in k_lastbel)
__global__ __launch_bounds__(128) void k_norm(float* __restrict__ alpha_b,
                                              const float* __restrict__ Gacc) {
  int row = blockIdx.x;                 // 4032 = 63 t * 64 n
  int t = row >> 6, n = row & 63;
  float inv = 1.f / Gacc[t*64 + n];
  float4* p = (float4*)(alpha_b + ((size_t)t*BB + n)*SS);
  float4 x = p[threadIdx.x];
  x.x *= inv; x.y *= inv; x.z *= inv; x.w *= inv;
  p[threadIdx.x] = x;
}

// ---------------- final belief (t=63) from X1 (apply invG(62))
__global__ __launch_bounds__(512) void k_lastbel(const float* __restrict__ X,
                                                 const float* __restrict__ lpo,
                                                 const float* __restrict__ Gacc,
                                                 float* __restrict__ alpha_b) {
  __shared__ float red[512];
  int n = blockIdx.x, j = threadIdx.x;
  float invG = 1.f / Gacc[62*64 + n];
  size_t off = (size_t)n*SS + j;
  float gv = fmaf(X[off], invG, EPS) * __expf(lpo[((size_t)63*BB + n)*SS + j]);
  red[j] = gv; __syncthreads();
  for (int s = 256; s > 0; s >>= 1) { if (j < s) red[j] += red[j+s]; __syncthreads(); }
  float inv = 1.f / red[0];
  alpha_b[((size_t)63*BB + n)*SS + j] = gv * inv;
}

// ---------------- plan(): 512 blocks (n x hk-eighth) x 256 thr, 8t x 2hk reg tile
__global__ __launch_bounds__(256) void k_pi(const float* __restrict__ alpha_b,
                                            const float* __restrict__ value,
                                            const float* __restrict__ pdf,
                                            float* __restrict__ alpha_pi) {
  __shared__ float Ab_l[64][132];   // i-tile of 128, pad 4
  __shared__ float lg[64][68];      // logits [t][hk_local 64]
  __shared__ float pdf_l[HH];
  int tid = threadIdx.x, bx = blockIdx.x;
  int n = bx >> 3, e = bx & 7;
  if (tid < HH) pdf_l[tid] = pdf[tid];
  int hkg = tid >> 3, tg = tid & 7;
  int hk0 = e*64 + hkg*2;
  const float* V0 = value + (((size_t)(hk0    >> 4)*BB + n)*AA + (hk0     & 15))*SS;
  const float* V1 = value + (((size_t)((hk0+1) >> 4)*BB + n)*AA + ((hk0+1) & 15))*SS;

  float4 a0[8], a1[8];
  #pragma unroll
  for (int m = 0; m < 8; m++) { a0[m] = make_float4(0,0,0,0); a1[m] = make_float4(0,0,0,0); }

  for (int it = 0; it < 4; it++) {
    __syncthreads();
    #pragma unroll
    for (int q = 0; q < 8; q++) {
      int idx = q*256 + tid;
      int tt = idx >> 5, il4 = (idx & 31)*4;
      float4 ab = *(const float4*)(alpha_b + ((size_t)tt*BB + n)*SS + it*128 + il4);
      *(float4*)&Ab_l[tt][il4] = ab;
    }
    __syncthreads();
    #pragma unroll 4
    for (int iq = 0; iq < 32; iq++) {
      float4 v0 = *(const float4*)(V0 + it*128 + iq*4);
      float4 v1 = *(const float4*)(V1 + it*128 + iq*4);
      #pragma unroll
      for (int tt = 0; tt < 8; tt++) {
        float4 ab = *(const float4*)&Ab_l[tt*8 + tg][iq*4];
        a0[tt].x = fmaf(ab.x, v0.x, a0[tt].x);
        a0[tt].y = fmaf(ab.y, v0.y, a0[tt].y);
        a0[tt].z = fmaf(ab.z, v0.z, a0[tt].z);
        a0[tt].w = fmaf(ab.w, v0.w, a0[tt].w);
        a1[tt].x = fmaf(ab.x, v1.x, a1[tt].x);
        a1[tt].y = fmaf(ab.y, v1.y, a1[tt].y);
        a1[tt].z = fmaf(ab.z, v1.z, a1[tt].z);
        a1[tt].w = fmaf(ab.w, v1.w, a1[tt].w);
      }
    }
  }
  #pragma unroll
  for (int tt = 0; tt < 8; tt++) {
    lg[tt*8 + tg][hkg*2 + 0] = a0[tt].x + a0[tt].y + a0[tt].z + a0[tt].w;
    lg[tt*8 + tg][hkg*2 + 1] = a1[tt].x + a1[tt].y + a1[tt].z + a1[tt].w;
  }
  __syncthreads();

  // softmax over k for (t, local h): 64t x 4h = 256 threads
  {
    int t = tid >> 2, hh = tid & 3;
    float* row = &lg[t][hh*16];
    float m = row[0];
    #pragma unroll
    for (int k2 = 1; k2 < 16; k2++) m = fmaxf(m, row[k2]);
    float ex[16]; float s = 0.f;
    #pragma unroll
    for (int k2 = 0; k2 < 16; k2++) { ex[k2] = __expf(row[k2]-m); s += ex[k2]; }
    float w = pdf_l[e*4 + hh] / s;
    #pragma unroll
    for (int k2 = 0; k2 < 16; k2++) row[k2] = ex[k2]*w;
  }
  __syncthreads();

  // combine 4 local h and atomic into alpha_pi
  #pragma unroll
  for (int q = 0; q < 4; q++) {
    int idx = q*256 + tid;           // 1024 = 64t x 16k
    int t = idx >> 4, k2 = idx & 15;
    float s = lg[t][0*16+k2] + lg[t][1*16+k2] + lg[t][2*16+k2] + lg[t][3*16+k2];
    atomicAdd(alpha_pi + ((size_t)t*BB + n)*AA + k2, s);
  }
}

extern "C" void kernel_launch(void* const* d_in, const int* in_sizes, int n_in,
                              void* d_out, int out_size, void* d_ws, size_t ws_size,
                              hipStream_t stream) {
  const float* lpo   = (const float*)d_in[0];
  const float* lpu   = (const float*)d_in[1];
  const float* value = (const float*)d_in[2];
  const float* b     = (const float*)d_in[3];
  const float* u     = (const float*)d_in[4];
  const float* v     = (const float*)d_in[5];
  const float* tau   = (const float*)d_in[6];
  float* out = (float*)d_out;
  float* ws  = (float*)d_ws;

  float* Tr  = ws + WS_TR;
  float* aT  = ws + WS_AT;
  float* pdf = ws + WS_PDF;
  float* X0  = ws + WS_X0;
  float* X1  = ws + WS_X1;
  float* X2  = ws + WS_X2;
  unsigned* bar = (unsigned*)(ws + WS_BAR);
  float* Gacc = ws + WS_G;

  float* alpha_b  = out;
  float* alpha_pi = out + (size_t)TT*BB*SS;

  hipLaunchKernelGGL(k_trans2,  dim3(512), dim3(256), 0, stream, u, v, Tr);
  hipLaunchKernelGGL(k_alpha_a, dim3(16),  dim3(256), 0, stream, lpu, aT);
  hipLaunchKernelGGL(k_taupdf,  dim3(1),   dim3(64),  0, stream, tau, pdf);
  hipLaunchKernelGGL(k_zero,    dim3(256), dim3(256), 0, stream, X1, X2, bar, alpha_pi, Gacc);

  void* args[10];
  args[0] = (void*)&Tr;  args[1] = (void*)&aT;  args[2] = (void*)&lpo;
  args[3] = (void*)&b;   args[4] = (void*)&X0;  args[5] = (void*)&X1;
  args[6] = (void*)&X2;  args[7] = (void*)&alpha_b; args[8] = (void*)&Gacc;
  args[9] = (void*)&bar;
  hipLaunchCooperativeKernel(k_scan, dim3(256), dim3(512), args, 0, stream);

  hipLaunchKernelGGL(k_norm,    dim3(4032), dim3(128), 0, stream, alpha_b, Gacc);
  hipLaunchKernelGGL(k_lastbel, dim3(64), dim3(512), 0, stream, X1, lpo, Gacc, alpha_b);
  hipLaunchKernelGGL(k_pi, dim3(512), dim3(256), 0, stream, alpha_b, value, pdf, alpha_pi);
}